// Round 3
// baseline (1022.008 us; speedup 1.0000x reference)
//
#include <hip/hip_runtime.h>
#include <hip/hip_bf16.h>

#define DEVI __device__ __forceinline__

typedef __bf16 bfrag __attribute__((ext_vector_type(8)));
typedef unsigned short us8 __attribute__((ext_vector_type(8)));
typedef float f32x4 __attribute__((ext_vector_type(4)));
typedef unsigned short ushort_t;

static constexpr int NB  = 16;
static constexpr int NH  = 8;
static constexpr int DIM = 1024;
static constexpr int DQh = 128;
static constexpr int ST  = 1024;
static constexpr int SM  = 2048;
static constexpr float INV_SCALE = 0.29730177875068026f; // 1 / 128^0.25
static constexpr float LN_EPS = 1e-5f;

DEVI ushort_t f2bf(float f) {
  __hip_bfloat16 h = __float2bfloat16(f);
  return __builtin_bit_cast(ushort_t, h);
}
DEVI float bf2f(ushort_t u) {
  return __bfloat162float(__builtin_bit_cast(__hip_bfloat16, u));
}
DEVI bfrag ldfrag(const ushort_t* p) {
  return __builtin_bit_cast(bfrag, *(const us8*)p);
}
DEVI void gl16(const ushort_t* g, ushort_t* l) {
  __builtin_amdgcn_global_load_lds(
      (const __attribute__((address_space(1))) void*)g,
      (__attribute__((address_space(3))) void*)l, 16, 0, 0);
}

enum { ST_BF16 = 0, ST_SWISH = 1, ST_F32RES = 2, ST_SCR = 3, ST_QKV = 4 };

// ---------------------------------------------------------------------------
// 256x256-tile 8-phase GEMM (T2+T3+T4+T5). C = A[M][K] x Bt[N][K]^T, bf16.
// 512 threads = 8 waves (2M x 4N), per-wave 128x64 output. BK=64, LDS ring of
// 4 k-half slots (256 rows x 32 k, 16 KB) per operand, double-buffered over
// tile parity. Counted vmcnt(4) at phases 4/8 only; never drains to 0.
// ---------------------------------------------------------------------------
template<int STORE>
__global__ __launch_bounds__(512)
void gemm256(const ushort_t* __restrict__ A, const ushort_t* __restrict__ Bt,
             const float* __restrict__ Res,
             ushort_t* __restrict__ P0, ushort_t* __restrict__ P1,
             ushort_t* __restrict__ P2, float* __restrict__ Cf,
             int M, int N, int K, int logS)
{
  __shared__ ushort_t Asl[4][8192];   // [parity*2+khalf][256 rows x 32 k]
  __shared__ ushort_t Bsl[4][8192];
  const int tid = threadIdx.x;
  int bx = blockIdx.x, by = blockIdx.y;
  {
    const int gx = gridDim.x;
    const int nwg = gx * gridDim.y;
    int bid = by * gx + bx;
    if ((nwg & 7) == 0) bid = (bid & 7) * (nwg >> 3) + (bid >> 3);  // XCD swizzle
    bx = bid % gx; by = bid / gx;
  }
  const int m0 = by * 256, n0 = bx * 256;

  const int lane = tid & 63;
  const int w  = tid >> 6;
  const int wm = w >> 2;        // 0..1
  const int wn = w & 3;         // 0..3
  const int frow = lane & 15;
  const int q    = lane >> 4;
  const int swz  = (frow >> 1) & 3;

  const ushort_t* Ab = A + (long)m0 * K;
  const ushort_t* Bb = Bt + (long)n0 * K;

  // staging constants: lane l of wave w fills granules w*128 + c*64 + l of a
  // 16 KB unit; source k-granule pre-swizzled with (row>>1)&3 == (l>>3)&3.
  const int sr0 = w * 32 + (lane >> 2);
  const int sg  = ((lane & 3) ^ ((lane >> 3) & 3)) * 8;
  const int ld0 = w * 1024;

  f32x4 acc[8][4];
  #pragma unroll
  for (int i = 0; i < 8; ++i)
    #pragma unroll
    for (int j = 0; j < 4; ++j) acc[i][j] = f32x4{0.f, 0.f, 0.f, 0.f};

  auto STG = [&](const ushort_t* G, int koff, ushort_t* unit) {
    gl16(G + (long)sr0 * K + koff + sg,        unit + ld0);
    gl16(G + (long)(sr0 + 16) * K + koff + sg, unit + ld0 + 512);
  };

  // prologue: tile0 (k0,k1) + tile1 (k0); wait for tile0 (all but 4 newest loads)
  STG(Ab, 0,  Asl[0]); STG(Bb, 0,  Bsl[0]);
  STG(Ab, 32, Asl[1]); STG(Bb, 32, Bsl[1]);
  STG(Ab, 64, Asl[2]); STG(Bb, 64, Bsl[2]);
  asm volatile("s_waitcnt vmcnt(4)" ::: "memory");
  __builtin_amdgcn_s_barrier();

  const int nk = K >> 6;  // 64-wide K-tiles; nk is even (K = 512 or 1024)
  for (int t = 0; t < nk; t += 2) {
    bfrag bf[4];
    #pragma unroll
    for (int ph = 0; ph < 8; ++ph) {
      const int tpar = (ph >> 2) & 1;     // tile parity (t is even)
      const int kh   = (ph >> 1) & 1;
      const int mh   = ph & 1;
      const ushort_t* Au = Asl[tpar * 2 + kh];
      const ushort_t* Bu = Bsl[tpar * 2 + kh];
      bfrag af[4];
      if (mh == 0) {
        #pragma unroll
        for (int j = 0; j < 4; ++j)
          bf[j] = ldfrag(Bu + (wn * 64 + j * 16 + frow) * 32 + ((q ^ swz) * 8));
      }
      #pragma unroll
      for (int i = 0; i < 4; ++i)
        af[i] = ldfrag(Au + (wm * 128 + mh * 64 + i * 16 + frow) * 32 + ((q ^ swz) * 8));

      // stage schedule (slot free-by-barrier and vmcnt-lead verified):
      if (ph == 0) STG(Ab, (t + 1) * 64 + 32, Asl[3]);
      if (ph == 1) STG(Bb, (t + 1) * 64 + 32, Bsl[3]);
      if (ph == 2 && t + 2 < nk) STG(Ab, (t + 2) * 64,      Asl[0]);
      if (ph == 3 && t + 2 < nk) STG(Bb, (t + 2) * 64,      Bsl[0]);
      if (ph == 4 && t + 2 < nk) STG(Ab, (t + 2) * 64 + 32, Asl[1]);
      if (ph == 5 && t + 2 < nk) STG(Bb, (t + 2) * 64 + 32, Bsl[1]);
      if (ph == 6 && t + 3 < nk) STG(Ab, (t + 3) * 64,      Asl[2]);
      if (ph == 7 && t + 3 < nk) STG(Bb, (t + 3) * 64,      Bsl[2]);

      if (ph == 3 || ph == 7) asm volatile("s_waitcnt vmcnt(4)" ::: "memory");
      __builtin_amdgcn_s_barrier();
      __builtin_amdgcn_s_setprio(1);
      #pragma unroll
      for (int i = 0; i < 4; ++i)
        #pragma unroll
        for (int j = 0; j < 4; ++j)
          acc[mh * 4 + i][j] =
              __builtin_amdgcn_mfma_f32_16x16x32_bf16(af[i], bf[j], acc[mh * 4 + i][j], 0, 0, 0);
      __builtin_amdgcn_s_setprio(0);
      __builtin_amdgcn_s_barrier();
    }
  }

  const int rb = (lane >> 4) * 4;
  #pragma unroll
  for (int mf = 0; mf < 8; ++mf) {
    #pragma unroll
    for (int j = 0; j < 4; ++j) {
      #pragma unroll
      for (int e = 0; e < 4; ++e) {
        const int gm = m0 + wm * 128 + mf * 16 + rb + e;
        const int gn = n0 + wn * 64 + j * 16 + frow;
        float val = acc[mf][j][e];
        if constexpr (STORE == ST_SWISH) val = val / (1.0f + __expf(-val));
        if constexpr (STORE == ST_BF16 || STORE == ST_SWISH) {
          P0[(long)gm * N + gn] = f2bf(val);
        } else if constexpr (STORE == ST_F32RES) {
          Cf[(long)gm * N + gn] = val + Res[(long)gm * N + gn];
        } else if constexpr (STORE == ST_QKV) {
          const int sel = gn >> 10;
          const int h   = (gn >> 7) & 7;
          const int dq  = gn & 127;
          ushort_t* Bq = (sel == 0) ? P0 : ((sel == 1) ? P1 : P2);
          const int S = 1 << logS;
          const int b = gm >> logS, s = gm & (S - 1);
          Bq[((long)(h * 16 + b) * S + (long)s) * 128 + dq] = f2bf(val);
        }
      }
    }
  }
}

// ---------------------------------------------------------------------------
// 128x128-tile GEMM (m97 structure) — kept for small-N shapes and scramble.
// ---------------------------------------------------------------------------
template<int STORE>
__global__ __launch_bounds__(256, 2)
void gemm_bb(const ushort_t* __restrict__ A, const ushort_t* __restrict__ Bt,
             const float* __restrict__ Res,
             ushort_t* __restrict__ Q0, float* __restrict__ Cf,
             int M, int N, int K, long aZ, long bZ)
{
  __shared__ ushort_t As[128][32];
  __shared__ ushort_t Bs[128][32];
  const int tid = threadIdx.x;
  int bx = blockIdx.x, by = blockIdx.y;
  if (gridDim.z == 1) {
    const int gx = gridDim.x;
    const int nwg = gx * gridDim.y;
    int bid = by * gx + bx;
    if ((nwg & 7) == 0) bid = (bid & 7) * (nwg >> 3) + (bid >> 3);
    bx = bid % gx; by = bid / gx;
  }
  const int z = blockIdx.z;
  const int m0 = by * 128, n0 = bx * 128;
  A  += aZ * (long)z;
  Bt += bZ * (long)z;

  const int lane = tid & 63;
  const int w = tid >> 6;
  const int wr = (w >> 1) * 64, wc = (w & 1) * 64;
  const int frow = lane & 15;

  const int grow = lane >> 2;
  const int gk = ((lane & 3) ^ ((lane >> 3) & 3)) * 8;
  const ushort_t* Ag = A + (long)(m0 + w * 32 + grow) * K + gk;
  const ushort_t* Bg = Bt + (long)(n0 + w * 32 + grow) * K + gk;

  f32x4 acc[4][4];
  #pragma unroll
  for (int i = 0; i < 4; ++i)
    #pragma unroll
    for (int j = 0; j < 4; ++j) acc[i][j] = f32x4{0.f, 0.f, 0.f, 0.f};

  const int kqs = ((frow >> 1) & 3);
  for (int k0 = 0; k0 < K; k0 += 32) {
    __syncthreads();
    gl16(Ag + k0,                &As[w * 32][0]);
    gl16(Ag + k0 + (long)16 * K, &As[w * 32 + 16][0]);
    gl16(Bg + k0,                &Bs[w * 32][0]);
    gl16(Bg + k0 + (long)16 * K, &Bs[w * 32 + 16][0]);
    __syncthreads();
    const int kq = (lane >> 4) ^ kqs;
    bfrag af[4], bf[4];
    #pragma unroll
    for (int i = 0; i < 4; ++i) af[i] = ldfrag(&As[wr + i * 16 + frow][kq * 8]);
    #pragma unroll
    for (int j = 0; j < 4; ++j) bf[j] = ldfrag(&Bs[wc + j * 16 + frow][kq * 8]);
    #pragma unroll
    for (int i = 0; i < 4; ++i)
      #pragma unroll
      for (int j = 0; j < 4; ++j)
        acc[i][j] = __builtin_amdgcn_mfma_f32_16x16x32_bf16(af[i], bf[j], acc[i][j], 0, 0, 0);
  }

  const int rb = (lane >> 4) * 4;
  #pragma unroll
  for (int i = 0; i < 4; ++i) {
    #pragma unroll
    for (int j = 0; j < 4; ++j) {
      #pragma unroll
      for (int e = 0; e < 4; ++e) {
        const int gm = m0 + wr + i * 16 + rb + e;
        const int gn = n0 + wc + j * 16 + frow;
        float val = acc[i][j][e];
        if constexpr (STORE == ST_BF16) {
          Q0[(long)gm * N + gn] = f2bf(val);
        } else if constexpr (STORE == ST_F32RES) {
          Cf[(long)gm * N + gn] = val + Res[(long)gm * N + gn];
        } else if constexpr (STORE == ST_SCR) {
          const int b = z & 15, hh = z >> 4;
          Q0[(long)b * (ST * DIM) + (long)(hh * 128 + (gm >> 3)) * DIM +
             (gm & 7) * 128 + gn] = f2bf(val);
        }
      }
    }
  }
}

// ---------------------------------------------------------------------------
// AmatT[z][e][d] = sum_s V[z][s][e] * softK[z][s][d]; bf16 in/out.
// ---------------------------------------------------------------------------
__global__ __launch_bounds__(256, 2)
void gemm_ktv(const ushort_t* __restrict__ Kp, const ushort_t* __restrict__ Vp,
              ushort_t* __restrict__ AT, int S)
{
  __shared__ ushort_t As[128][40];
  __shared__ ushort_t Bs[128][40];
  const int tid = threadIdx.x;
  const int z = blockIdx.x;
  const ushort_t* Vb = Vp + (long)z * S * DQh;
  const ushort_t* Kb = Kp + (long)z * S * DQh;
  const int lane = tid & 63;
  const int wr = ((tid >> 6) >> 1) * 64, wc = ((tid >> 6) & 1) * 64;
  const int frow = lane & 15, fk = (lane >> 4) * 8;
  const int c = tid & 127;
  const int sr0 = tid >> 7;

  f32x4 acc[4][4];
  #pragma unroll
  for (int i = 0; i < 4; ++i)
    #pragma unroll
    for (int j = 0; j < 4; ++j) acc[i][j] = f32x4{0.f, 0.f, 0.f, 0.f};

  for (int s0 = 0; s0 < S; s0 += 32) {
    __syncthreads();
    #pragma unroll
    for (int p = 0; p < 16; ++p) {
      const int sr = sr0 + p * 2;
      As[c][sr] = Vb[(long)(s0 + sr) * DQh + c];
      Bs[c][sr] = Kb[(long)(s0 + sr) * DQh + c];
    }
    __syncthreads();
    bfrag af[4], bfv[4];
    #pragma unroll
    for (int i = 0; i < 4; ++i) af[i]  = ldfrag(&As[wr + i * 16 + frow][fk]);
    #pragma unroll
    for (int j = 0; j < 4; ++j) bfv[j] = ldfrag(&Bs[wc + j * 16 + frow][fk]);
    #pragma unroll
    for (int i = 0; i < 4; ++i)
      #pragma unroll
      for (int j = 0; j < 4; ++j)
        acc[i][j] = __builtin_amdgcn_mfma_f32_16x16x32_bf16(af[i], bfv[j], acc[i][j], 0, 0, 0);
  }
  const int rb = (lane >> 4) * 4;
  #pragma unroll
  for (int i = 0; i < 4; ++i)
    #pragma unroll
    for (int j = 0; j < 4; ++j)
      #pragma unroll
      for (int e = 0; e < 4; ++e)
        AT[(long)z * 16384 + (long)(wr + i * 16 + rb + e) * 128 + (wc + j * 16 + frow)] =
            f2bf(acc[i][j][e]);
}

template<bool MASKED>
__global__ __launch_bounds__(256)
void softmax128(ushort_t* __restrict__ X, int smask)
{
  const int row = blockIdx.x * 4 + (threadIdx.x >> 6);
  const int lane = threadIdx.x & 63;
  ushort_t* xr = X + (long)row * 128;
  float x0 = bf2f(xr[lane]) * INV_SCALE;
  float x1 = bf2f(xr[lane + 64]) * INV_SCALE;
  if constexpr (MASKED) {
    const int s = row & smask;
    if (lane > s)      x0 = -3.0e38f;
    if (lane + 64 > s) x1 = -3.0e38f;
  }
  float mx = fmaxf(x0, x1);
  #pragma unroll
  for (int o = 32; o; o >>= 1) mx = fmaxf(mx, __shfl_xor(mx, o));
  const float e0 = __expf(x0 - mx);
  const float e1 = __expf(x1 - mx);
  float sm = e0 + e1;
  #pragma unroll
  for (int o = 32; o; o >>= 1) sm += __shfl_xor(sm, o);
  const float inv = 1.0f / sm;
  xr[lane]      = f2bf(e0 * inv);
  xr[lane + 64] = f2bf(e1 * inv);
}

__global__ __launch_bounds__(256)
void layernorm_k(const float* __restrict__ X, const float* __restrict__ G,
                 const float* __restrict__ Bta, float* __restrict__ Y,
                 ushort_t* __restrict__ Yb)
{
  const int row = blockIdx.x;
  const int t = threadIdx.x;
  const float4 v = *(const float4*)(X + (long)row * DIM + t * 4);
  float s  = v.x + v.y + v.z + v.w;
  float sq = v.x * v.x + v.y * v.y + v.z * v.z + v.w * v.w;
  #pragma unroll
  for (int o = 32; o; o >>= 1) { s += __shfl_xor(s, o); sq += __shfl_xor(sq, o); }
  __shared__ float ps[4], pq[4];
  if ((t & 63) == 0) { ps[t >> 6] = s; pq[t >> 6] = sq; }
  __syncthreads();
  s  = ps[0] + ps[1] + ps[2] + ps[3];
  sq = pq[0] + pq[1] + pq[2] + pq[3];
  const float mean = s * (1.0f / DIM);
  const float var  = sq * (1.0f / DIM) - mean * mean;
  const float rstd = rsqrtf(var + LN_EPS);
  const float4 gv = *(const float4*)(G + t * 4);
  const float4 bv = *(const float4*)(Bta + t * 4);
  float4 o;
  o.x = (v.x - mean) * rstd * gv.x + bv.x;
  o.y = (v.y - mean) * rstd * gv.y + bv.y;
  o.z = (v.z - mean) * rstd * gv.z + bv.z;
  o.w = (v.w - mean) * rstd * gv.w + bv.w;
  *(float4*)(Y + (long)row * DIM + t * 4) = o;
  if (Yb) {
    ushort4 ob = make_ushort4(f2bf(o.x), f2bf(o.y), f2bf(o.z), f2bf(o.w));
    *(ushort4*)(Yb + (long)row * DIM + t * 4) = ob;
  }
}

__global__ __launch_bounds__(256)
void transpose_cast(const float* __restrict__ W, ushort_t* __restrict__ Wt)
{
  __shared__ float tile[32][33];
  const int z = blockIdx.z;
  const int kb = blockIdx.y * 32;
  const int nb = blockIdx.x * 32;
  const float* src = W + (long)z * DIM * DQh;
  ushort_t* dst = Wt + (long)z * DIM * DQh;
  const int tx = threadIdx.x & 31;
  const int ty = threadIdx.x >> 5;
  #pragma unroll
  for (int r = 0; r < 32; r += 8)
    tile[ty + r][tx] = src[(long)(kb + ty + r) * DQh + nb + tx];
  __syncthreads();
  #pragma unroll
  for (int r = 0; r < 32; r += 8)
    dst[(long)(nb + ty + r) * DIM + kb + tx] = f2bf(tile[tx][ty + r]);
}

__global__ __launch_bounds__(256)
void cast_bf16(const float* __restrict__ X, ushort_t* __restrict__ Yq)
{
  const long i = ((long)blockIdx.x * 256 + threadIdx.x) * 4;
  const float4 v = *(const float4*)(X + i);
  ushort4 sv = make_ushort4(f2bf(v.x), f2bf(v.y), f2bf(v.z), f2bf(v.w));
  *(ushort4*)(Yq + i) = sv;
}

// ---------------------------------------------------------------------------

extern "C" void kernel_launch(void* const* d_in, const int* in_sizes, int n_in,
                              void* d_out, int out_size, void* d_ws, size_t ws_size,
                              hipStream_t stream)
{
  (void)in_sizes; (void)n_in; (void)out_size; (void)ws_size;
  const float* mem = (const float*)d_in[0];
  const float* y0  = (const float*)d_in[1];
  const float* Wq1 = (const float*)d_in[2];
  const float* Wk1 = (const float*)d_in[3];
  const float* Wv1 = (const float*)d_in[4];
  const float* Wo1 = (const float*)d_in[5];
  const float* Wq2 = (const float*)d_in[6];
  const float* Wk2 = (const float*)d_in[7];
  const float* Wv2 = (const float*)d_in[8];
  const float* Wo2 = (const float*)d_in[9];
  const float* E1  = (const float*)d_in[10];
  const float* D1  = (const float*)d_in[11];
  const float* E2  = (const float*)d_in[12];
  const float* D2  = (const float*)d_in[13];
  const float* g1  = (const float*)d_in[14];
  const float* b1  = (const float*)d_in[15];
  const float* g2  = (const float*)d_in[16];
  const float* b2  = (const float*)d_in[17];
  const float* g3  = (const float*)d_in[18];
  const float* b3  = (const float*)d_in[19];

  char* ws = (char*)d_ws;
  const size_t MB = 1ull << 20;
  ushort_t* wcat1 = (ushort_t*)(ws + 0 * MB);    // [3072][1024]
  ushort_t* wkv2  = (ushort_t*)(ws + 6 * MB);    // [2048][1024]
  ushort_t* wq2t  = (ushort_t*)(ws + 10 * MB);
  ushort_t* wo1b  = (ushort_t*)(ws + 12 * MB);
  ushort_t* wo2b  = (ushort_t*)(ws + 14 * MB);
  ushort_t* e1b   = (ushort_t*)(ws + 16 * MB);
  ushort_t* d1b   = (ushort_t*)(ws + 17 * MB);
  ushort_t* e2b   = (ushort_t*)(ws + 18 * MB);
  ushort_t* d2b   = (ushort_t*)(ws + 19 * MB);
  ushort_t* y0b   = (ushort_t*)(ws + 20 * MB);
  ushort_t* memb  = (ushort_t*)(ws + 52 * MB);
  ushort_t* qbuf  = (ushort_t*)(ws + 116 * MB);
  ushort_t* kbuf  = (ushort_t*)(ws + 148 * MB);
  ushort_t* vbuf  = (ushort_t*)(ws + 212 * MB);
  ushort_t* amatT = (ushort_t*)(ws + 276 * MB);
  ushort_t* attnb = (ushort_t*)(ws + 280 * MB);
  float*    ybuf  = (float*)(ws + 312 * MB);
  ushort_t* ybf   = (ushort_t*)(ws + 376 * MB);
  ushort_t* hbuf  = (ushort_t*)(ws + 408 * MB);
  ushort_t* bn1   = attnb;
  ushort_t* bn2   = qbuf;

  // ---- prep ----
  cast_bf16<<<16384, 256, 0, stream>>>(y0, y0b);
  cast_bf16<<<32768, 256, 0, stream>>>(mem, memb);
  transpose_cast<<<dim3(4, 32, 8), 256, 0, stream>>>(Wq1, wcat1);
  transpose_cast<<<dim3(4, 32, 8), 256, 0, stream>>>(Wk1, wcat1 + (1 << 20));
  transpose_cast<<<dim3(4, 32, 8), 256, 0, stream>>>(Wv1, wcat1 + (2 << 20));
  transpose_cast<<<dim3(4, 32, 8), 256, 0, stream>>>(Wk2, wkv2);
  transpose_cast<<<dim3(4, 32, 8), 256, 0, stream>>>(Wv2, wkv2 + (1 << 20));
  transpose_cast<<<dim3(4, 32, 8), 256, 0, stream>>>(Wq2, wq2t);
  cast_bf16<<<1024, 256, 0, stream>>>(Wo1, wo1b);
  cast_bf16<<<1024, 256, 0, stream>>>(Wo2, wo2b);
  cast_bf16<<<512, 256, 0, stream>>>(E1, e1b);
  cast_bf16<<<512, 256, 0, stream>>>(D1, d1b);
  cast_bf16<<<512, 256, 0, stream>>>(E2, e2b);
  cast_bf16<<<512, 256, 0, stream>>>(D2, d2b);

  // ---- phase 1: masked self linear-attention ----
  gemm256<ST_QKV><<<dim3(12, 64), 512, 0, stream>>>(
      y0b, wcat1, nullptr, qbuf, kbuf, vbuf, nullptr, NB * ST, 3072, DIM, 10);
  softmax128<true><<<NH * NB * ST / 4, 256, 0, stream>>>(qbuf, ST - 1);
  softmax128<false><<<NH * NB * ST / 4, 256, 0, stream>>>(kbuf, 0);
  gemm_ktv<<<NH * NB, 256, 0, stream>>>(kbuf, vbuf, amatT, ST);
  gemm_bb<ST_SCR><<<dim3(1, 8, 128), 256, 0, stream>>>(
      qbuf, amatT, nullptr, attnb, nullptr, ST, DQh, DQh, (long)ST * DQh, 16384);
  gemm256<ST_F32RES><<<dim3(4, 64), 512, 0, stream>>>(
      attnb, wo1b, y0, nullptr, nullptr, nullptr, ybuf, NB * ST, DIM, DIM, 0);
  layernorm_k<<<NB * ST, 256, 0, stream>>>(ybuf, g1, b1, ybuf, ybf);

  // ---- phase 2: cross linear-attention ----
  gemm256<ST_QKV><<<dim3(4, 64), 512, 0, stream>>>(
      ybf, wq2t, nullptr, qbuf, nullptr, nullptr, nullptr, NB * ST, 1024, DIM, 10);
  gemm256<ST_QKV><<<dim3(8, 128), 512, 0, stream>>>(
      memb, wkv2, nullptr, kbuf, vbuf, nullptr, nullptr, NB * SM, 2048, DIM, 11);
  softmax128<false><<<NH * NB * ST / 4, 256, 0, stream>>>(qbuf, 0);
  softmax128<false><<<NH * NB * SM / 4, 256, 0, stream>>>(kbuf, 0);
  gemm_ktv<<<NH * NB, 256, 0, stream>>>(kbuf, vbuf, amatT, SM);
  gemm_bb<ST_SCR><<<dim3(1, 8, 128), 256, 0, stream>>>(
      qbuf, amatT, nullptr, attnb, nullptr, ST, DQh, DQh, (long)ST * DQh, 16384);
  gemm256<ST_F32RES><<<dim3(4, 64), 512, 0, stream>>>(
      attnb, wo2b, ybuf, nullptr, nullptr, nullptr, ybuf, NB * ST, DIM, DIM, 0);
  layernorm_k<<<NB * ST, 256, 0, stream>>>(ybuf, g2, b2, ybuf, ybf);

  // ---- phase 3: LFFN ----
  gemm_bb<ST_BF16><<<dim3(4, 128, 1), 256, 0, stream>>>(
      ybf, e1b, nullptr, bn1, nullptr, NB * ST, 512, DIM, 0, 0);
  gemm256<ST_SWISH><<<dim3(4, 64), 512, 0, stream>>>(
      bn1, d1b, nullptr, hbuf, nullptr, nullptr, nullptr, NB * ST, DIM, 512, 0);
  gemm_bb<ST_BF16><<<dim3(4, 128, 1), 256, 0, stream>>>(
      hbuf, e2b, nullptr, bn2, nullptr, NB * ST, 512, DIM, 0, 0);
  gemm256<ST_F32RES><<<dim3(4, 64), 512, 0, stream>>>(
      bn2, d2b, ybuf, nullptr, nullptr, nullptr, ybuf, NB * ST, DIM, 512, 0);
  layernorm_k<<<NB * ST, 256, 0, stream>>>(ybuf, g3, b3, (float*)d_out, nullptr);
}

// Round 4
// 958.757 us; speedup vs baseline: 1.0660x; 1.0660x over previous
//
#include <hip/hip_runtime.h>
#include <hip/hip_bf16.h>

#define DEVI __device__ __forceinline__

typedef __bf16 bfrag __attribute__((ext_vector_type(8)));
typedef unsigned short us8 __attribute__((ext_vector_type(8)));
typedef float f32x4 __attribute__((ext_vector_type(4)));
typedef unsigned short ushort_t;

static constexpr int NB  = 16;
static constexpr int NH  = 8;
static constexpr int DIM = 1024;
static constexpr int DQh = 128;
static constexpr int ST  = 1024;
static constexpr int SM  = 2048;
static constexpr float INV_SCALE = 0.29730177875068026f; // 1 / 128^0.25
static constexpr float LN_EPS = 1e-5f;

DEVI ushort_t f2bf(float f) {
  __hip_bfloat16 h = __float2bfloat16(f);
  return __builtin_bit_cast(ushort_t, h);
}
DEVI float bf2f(ushort_t u) {
  return __bfloat162float(__builtin_bit_cast(__hip_bfloat16, u));
}
DEVI bfrag ldfrag(const ushort_t* p) {
  return __builtin_bit_cast(bfrag, *(const us8*)p);
}
DEVI void gl16(const ushort_t* g, ushort_t* l) {
  __builtin_amdgcn_global_load_lds(
      (const __attribute__((address_space(1))) void*)g,
      (__attribute__((address_space(3))) void*)l, 16, 0, 0);
}

enum { ST_BF16 = 0, ST_SWISH = 1, ST_RESB = 2, ST_SCR = 3, ST_QKV = 4 };

// ---------------------------------------------------------------------------
// 128x128-tile bf16 GEMM (m97 structure), 4 waves. Epilogue variants:
//  ST_BF16  : plain bf16 store
//  ST_SWISH : swish then bf16
//  ST_RESB  : + bf16 residual, bf16 store
//  ST_SCR   : torch .view head-merge scramble store
//  ST_QKV   : scatter to per-(h,b) [S][128] buffers with OPTIONAL fused
//             row-softmax over the head dim (cross-wave-pair LDS reduce),
//             optional causal head-dim mask (phase-1 Q).
// ---------------------------------------------------------------------------
template<int STORE>
__global__ __launch_bounds__(256, 2)
void gemm_bb(const ushort_t* __restrict__ A, const ushort_t* __restrict__ Bt,
             const ushort_t* __restrict__ ResB,
             ushort_t* __restrict__ P0, ushort_t* __restrict__ P1,
             ushort_t* __restrict__ P2,
             int M, int N, int K, long aZ, long bZ,
             int logS, int smflags, int maskflags)
{
  __shared__ ushort_t As[128][32];
  __shared__ ushort_t Bs[128][32];
  __shared__ float msx[4][64][2];
  const int tid = threadIdx.x;
  int bx = blockIdx.x, by = blockIdx.y;
  if (gridDim.z == 1) {
    const int gx = gridDim.x;
    const int nwg = gx * gridDim.y;
    int bid = by * gx + bx;
    if ((nwg & 7) == 0) bid = (bid & 7) * (nwg >> 3) + (bid >> 3);  // XCD swizzle
    bx = bid % gx; by = bid / gx;
  }
  const int z = blockIdx.z;
  const int m0 = by * 128, n0 = bx * 128;
  A  += aZ * (long)z;
  Bt += bZ * (long)z;

  const int lane = tid & 63;
  const int w = tid >> 6;
  const int wr = (w >> 1) * 64, wc = (w & 1) * 64;
  const int frow = lane & 15;
  const int q = lane >> 4;

  const int grow = lane >> 2;
  const int gk = ((lane & 3) ^ ((lane >> 3) & 3)) * 8;
  const ushort_t* Ag = A + (long)(m0 + w * 32 + grow) * K + gk;
  const ushort_t* Bg = Bt + (long)(n0 + w * 32 + grow) * K + gk;

  f32x4 acc[4][4];
  #pragma unroll
  for (int i = 0; i < 4; ++i)
    #pragma unroll
    for (int j = 0; j < 4; ++j) acc[i][j] = f32x4{0.f, 0.f, 0.f, 0.f};

  const int kqs = ((frow >> 1) & 3);
  for (int k0 = 0; k0 < K; k0 += 32) {
    __syncthreads();
    gl16(Ag + k0,                &As[w * 32][0]);
    gl16(Ag + k0 + (long)16 * K, &As[w * 32 + 16][0]);
    gl16(Bg + k0,                &Bs[w * 32][0]);
    gl16(Bg + k0 + (long)16 * K, &Bs[w * 32 + 16][0]);
    __syncthreads();
    const int kq = (q ^ kqs);
    bfrag af[4], bf[4];
    #pragma unroll
    for (int i = 0; i < 4; ++i) af[i] = ldfrag(&As[wr + i * 16 + frow][kq * 8]);
    #pragma unroll
    for (int j = 0; j < 4; ++j) bf[j] = ldfrag(&Bs[wc + j * 16 + frow][kq * 8]);
    #pragma unroll
    for (int i = 0; i < 4; ++i)
      #pragma unroll
      for (int j = 0; j < 4; ++j)
        acc[i][j] = __builtin_amdgcn_mfma_f32_16x16x32_bf16(af[i], bf[j], acc[i][j], 0, 0, 0);
  }

  const int rb = q * 4;
  if constexpr (STORE == ST_QKV) {
    const int sel = n0 >> 10;  // block-uniform
    const bool dosm   = (smflags >> sel) & 1;
    const bool domask = (maskflags >> sel) & 1;
    const int smask = (1 << logS) - 1;
    if (dosm) {
      // scale + optional mask
      #pragma unroll
      for (int i = 0; i < 4; ++i)
        #pragma unroll
        for (int e = 0; e < 4; ++e) {
          const int slim = (m0 + wr + i * 16 + rb + e) & smask;
          #pragma unroll
          for (int j = 0; j < 4; ++j) {
            const int dq = wc + j * 16 + frow;  // 0..127 within head
            float v = acc[i][j][e] * INV_SCALE;
            if (domask && dq > slim) v = -3.0e38f;
            acc[i][j][e] = v;
          }
        }
      float m_ie[4][4], s_ie[4][4];
      #pragma unroll
      for (int i = 0; i < 4; ++i)
        #pragma unroll
        for (int e = 0; e < 4; ++e) {
          float m = fmaxf(fmaxf(acc[i][0][e], acc[i][1][e]),
                          fmaxf(acc[i][2][e], acc[i][3][e]));
          m = fmaxf(m, __shfl_xor(m, 1));
          m = fmaxf(m, __shfl_xor(m, 2));
          m = fmaxf(m, __shfl_xor(m, 4));
          m = fmaxf(m, __shfl_xor(m, 8));
          m_ie[i][e] = m;
        }
      #pragma unroll
      for (int i = 0; i < 4; ++i)
        #pragma unroll
        for (int j = 0; j < 4; ++j)
          #pragma unroll
          for (int e = 0; e < 4; ++e)
            acc[i][j][e] = __expf(acc[i][j][e] - m_ie[i][e]);
      #pragma unroll
      for (int i = 0; i < 4; ++i)
        #pragma unroll
        for (int e = 0; e < 4; ++e) {
          float s = acc[i][0][e] + acc[i][1][e] + acc[i][2][e] + acc[i][3][e];
          s += __shfl_xor(s, 1);
          s += __shfl_xor(s, 2);
          s += __shfl_xor(s, 4);
          s += __shfl_xor(s, 8);
          s_ie[i][e] = s;
        }
      if (frow == 0) {
        #pragma unroll
        for (int i = 0; i < 4; ++i)
          #pragma unroll
          for (int e = 0; e < 4; ++e) {
            msx[w][i * 16 + rb + e][0] = m_ie[i][e];
            msx[w][i * 16 + rb + e][1] = s_ie[i][e];
          }
      }
      __syncthreads();
      #pragma unroll
      for (int i = 0; i < 4; ++i)
        #pragma unroll
        for (int e = 0; e < 4; ++e) {
          const int idx = i * 16 + rb + e;
          const float mo = msx[w ^ 1][idx][0];
          const float so = msx[w ^ 1][idx][1];
          const float mj = fmaxf(m_ie[i][e], mo);
          const float sj = s_ie[i][e] * __expf(m_ie[i][e] - mj) +
                           so * __expf(mo - mj);
          m_ie[i][e] = __expf(m_ie[i][e] - mj) / sj;  // reuse as factor
        }
      #pragma unroll
      for (int i = 0; i < 4; ++i)
        #pragma unroll
        for (int j = 0; j < 4; ++j)
          #pragma unroll
          for (int e = 0; e < 4; ++e)
            acc[i][j][e] *= m_ie[i][e];
    }
    const int h = (n0 >> 7) & 7;
    ushort_t* __restrict__ Bq = (sel == 0) ? P0 : ((sel == 1) ? P1 : P2);
    const int S = 1 << logS;
    #pragma unroll
    for (int i = 0; i < 4; ++i)
      #pragma unroll
      for (int j = 0; j < 4; ++j)
        #pragma unroll
        for (int e = 0; e < 4; ++e) {
          const int gm = m0 + wr + i * 16 + rb + e;
          const int dq = wc + j * 16 + frow;
          const int b = gm >> logS, s = gm & (S - 1);
          Bq[((long)(h * 16 + b) * S + (long)s) * 128 + dq] = f2bf(acc[i][j][e]);
        }
  } else {
    #pragma unroll
    for (int i = 0; i < 4; ++i) {
      #pragma unroll
      for (int j = 0; j < 4; ++j) {
        #pragma unroll
        for (int e = 0; e < 4; ++e) {
          const int gm = m0 + wr + i * 16 + rb + e;
          const int gn = n0 + wc + j * 16 + frow;
          float val = acc[i][j][e];
          if constexpr (STORE == ST_SWISH) val = val / (1.0f + __expf(-val));
          if constexpr (STORE == ST_RESB)  val += bf2f(ResB[(long)gm * N + gn]);
          if constexpr (STORE == ST_SCR) {
            const int b = z & 15, hh = z >> 4;
            P0[(long)b * (ST * DIM) + (long)(hh * 128 + (gm >> 3)) * DIM +
               (gm & 7) * 128 + gn] = f2bf(val);
          } else {
            P0[(long)gm * N + gn] = f2bf(val);
          }
        }
      }
    }
  }
}

// ---------------------------------------------------------------------------
// Split-S K^T·V: P[ch][z][e][d] = sum_{s in chunk} V[z][s][e]*softK[z][s][d]
// f32 partials; grid (z=128, nch).
// ---------------------------------------------------------------------------
__global__ __launch_bounds__(256, 2)
void gemm_ktv(const ushort_t* __restrict__ Kp, const ushort_t* __restrict__ Vp,
              float* __restrict__ P, int S, int SC)
{
  __shared__ ushort_t As[128][40];
  __shared__ ushort_t Bs[128][40];
  const int tid = threadIdx.x;
  const int z = blockIdx.x;
  const int ch = blockIdx.y;
  const long base = ((long)z * S + (long)ch * SC) * DQh;
  const ushort_t* Vb = Vp + base;
  const ushort_t* Kb = Kp + base;
  const int lane = tid & 63;
  const int wr = ((tid >> 6) >> 1) * 64, wc = ((tid >> 6) & 1) * 64;
  const int frow = lane & 15, fk = (lane >> 4) * 8;
  const int c = tid & 127;
  const int sr0 = tid >> 7;

  f32x4 acc[4][4];
  #pragma unroll
  for (int i = 0; i < 4; ++i)
    #pragma unroll
    for (int j = 0; j < 4; ++j) acc[i][j] = f32x4{0.f, 0.f, 0.f, 0.f};

  for (int s0 = 0; s0 < SC; s0 += 32) {
    __syncthreads();
    #pragma unroll
    for (int p = 0; p < 16; ++p) {
      const int sr = sr0 + p * 2;
      As[c][sr] = Vb[(long)(s0 + sr) * DQh + c];
      Bs[c][sr] = Kb[(long)(s0 + sr) * DQh + c];
    }
    __syncthreads();
    bfrag af[4], bfv[4];
    #pragma unroll
    for (int i = 0; i < 4; ++i) af[i]  = ldfrag(&As[wr + i * 16 + frow][fk]);
    #pragma unroll
    for (int j = 0; j < 4; ++j) bfv[j] = ldfrag(&Bs[wc + j * 16 + frow][fk]);
    #pragma unroll
    for (int i = 0; i < 4; ++i)
      #pragma unroll
      for (int j = 0; j < 4; ++j)
        acc[i][j] = __builtin_amdgcn_mfma_f32_16x16x32_bf16(af[i], bfv[j], acc[i][j], 0, 0, 0);
  }
  float* Pz = P + ((long)ch * 128 + z) * 16384;
  const int rb = (lane >> 4) * 4;
  #pragma unroll
  for (int i = 0; i < 4; ++i)
    #pragma unroll
    for (int j = 0; j < 4; ++j)
      #pragma unroll
      for (int e = 0; e < 4; ++e)
        Pz[(long)(wr + i * 16 + rb + e) * 128 + (wc + j * 16 + frow)] = acc[i][j][e];
}

// sum partials over chunks, cast bf16. total 128*16384 elems.
__global__ __launch_bounds__(256)
void ktv_reduce(const float* __restrict__ P, ushort_t* __restrict__ AT, int nch)
{
  const long i = ((long)blockIdx.x * 256 + threadIdx.x) * 4;
  float4 s = *(const float4*)(P + i);
  for (int c = 1; c < nch; ++c) {
    const float4 v = *(const float4*)(P + (long)c * 2097152 + i);
    s.x += v.x; s.y += v.y; s.z += v.z; s.w += v.w;
  }
  ushort4 o = make_ushort4(f2bf(s.x), f2bf(s.y), f2bf(s.z), f2bf(s.w));
  *(ushort4*)(AT + i) = o;
}

// ---------------------------------------------------------------------------
// LayerNorm over DIM=1024, bf16 in; bf16 out (Yb) and/or f32 out (Yf).
// ---------------------------------------------------------------------------
__global__ __launch_bounds__(256)
void layernorm_b(const ushort_t* __restrict__ X, const float* __restrict__ G,
                 const float* __restrict__ Bta, ushort_t* __restrict__ Yb,
                 float* __restrict__ Yf)
{
  const int row = blockIdx.x;
  const int t = threadIdx.x;
  const ushort4 xu = *(const ushort4*)(X + (long)row * DIM + t * 4);
  float x0 = bf2f(xu.x), x1 = bf2f(xu.y), x2 = bf2f(xu.z), x3 = bf2f(xu.w);
  float s  = x0 + x1 + x2 + x3;
  float sq = x0 * x0 + x1 * x1 + x2 * x2 + x3 * x3;
  #pragma unroll
  for (int o = 32; o; o >>= 1) { s += __shfl_xor(s, o); sq += __shfl_xor(sq, o); }
  __shared__ float ps[4], pq[4];
  if ((t & 63) == 0) { ps[t >> 6] = s; pq[t >> 6] = sq; }
  __syncthreads();
  s  = ps[0] + ps[1] + ps[2] + ps[3];
  sq = pq[0] + pq[1] + pq[2] + pq[3];
  const float mean = s * (1.0f / DIM);
  const float var  = sq * (1.0f / DIM) - mean * mean;
  const float rstd = rsqrtf(var + LN_EPS);
  const float4 gv = *(const float4*)(G + t * 4);
  const float4 bv = *(const float4*)(Bta + t * 4);
  float o0 = (x0 - mean) * rstd * gv.x + bv.x;
  float o1 = (x1 - mean) * rstd * gv.y + bv.y;
  float o2 = (x2 - mean) * rstd * gv.z + bv.z;
  float o3 = (x3 - mean) * rstd * gv.w + bv.w;
  if (Yb) {
    ushort4 ob = make_ushort4(f2bf(o0), f2bf(o1), f2bf(o2), f2bf(o3));
    *(ushort4*)(Yb + (long)row * DIM + t * 4) = ob;
  }
  if (Yf) {
    float4 of; of.x = o0; of.y = o1; of.z = o2; of.w = o3;
    *(float4*)(Yf + (long)row * DIM + t * 4) = of;
  }
}

// Weight prep: [H][DIM][DQh] f32 -> rows (h*128+dq), cols k, bf16
__global__ __launch_bounds__(256)
void transpose_cast(const float* __restrict__ W, ushort_t* __restrict__ Wt)
{
  __shared__ float tile[32][33];
  const int z = blockIdx.z;
  const int kb = blockIdx.y * 32;
  const int nb = blockIdx.x * 32;
  const float* src = W + (long)z * DIM * DQh;
  ushort_t* dst = Wt + (long)z * DIM * DQh;
  const int tx = threadIdx.x & 31;
  const int ty = threadIdx.x >> 5;
  #pragma unroll
  for (int r = 0; r < 32; r += 8)
    tile[ty + r][tx] = src[(long)(kb + ty + r) * DQh + nb + tx];
  __syncthreads();
  #pragma unroll
  for (int r = 0; r < 32; r += 8)
    dst[(long)(nb + ty + r) * DIM + kb + tx] = f2bf(tile[tx][ty + r]);
}

__global__ __launch_bounds__(256)
void cast_bf16(const float* __restrict__ X, ushort_t* __restrict__ Yq)
{
  const long i = ((long)blockIdx.x * 256 + threadIdx.x) * 4;
  const float4 v = *(const float4*)(X + i);
  ushort4 sv = make_ushort4(f2bf(v.x), f2bf(v.y), f2bf(v.z), f2bf(v.w));
  *(ushort4*)(Yq + i) = sv;
}

// ---------------------------------------------------------------------------

extern "C" void kernel_launch(void* const* d_in, const int* in_sizes, int n_in,
                              void* d_out, int out_size, void* d_ws, size_t ws_size,
                              hipStream_t stream)
{
  (void)in_sizes; (void)n_in; (void)out_size; (void)ws_size;
  const float* mem = (const float*)d_in[0];
  const float* y0  = (const float*)d_in[1];
  const float* Wq1 = (const float*)d_in[2];
  const float* Wk1 = (const float*)d_in[3];
  const float* Wv1 = (const float*)d_in[4];
  const float* Wo1 = (const float*)d_in[5];
  const float* Wq2 = (const float*)d_in[6];
  const float* Wk2 = (const float*)d_in[7];
  const float* Wv2 = (const float*)d_in[8];
  const float* Wo2 = (const float*)d_in[9];
  const float* E1  = (const float*)d_in[10];
  const float* D1  = (const float*)d_in[11];
  const float* E2  = (const float*)d_in[12];
  const float* D2  = (const float*)d_in[13];
  const float* g1  = (const float*)d_in[14];
  const float* b1  = (const float*)d_in[15];
  const float* g2  = (const float*)d_in[16];
  const float* b2  = (const float*)d_in[17];
  const float* g3  = (const float*)d_in[18];
  const float* b3  = (const float*)d_in[19];

  char* ws = (char*)d_ws;
  const size_t MB = 1ull << 20;
  ushort_t* wcat1 = (ushort_t*)(ws + 0 * MB);    // [3072][1024]
  ushort_t* wkv2  = (ushort_t*)(ws + 6 * MB);    // [2048][1024]
  ushort_t* wq2t  = (ushort_t*)(ws + 10 * MB);
  ushort_t* wo1b  = (ushort_t*)(ws + 12 * MB);
  ushort_t* wo2b  = (ushort_t*)(ws + 14 * MB);
  ushort_t* e1b   = (ushort_t*)(ws + 16 * MB);
  ushort_t* d1b   = (ushort_t*)(ws + 17 * MB);
  ushort_t* e2b   = (ushort_t*)(ws + 18 * MB);
  ushort_t* d2b   = (ushort_t*)(ws + 19 * MB);
  ushort_t* y0b   = (ushort_t*)(ws + 20 * MB);   // 32 MB
  ushort_t* memb  = (ushort_t*)(ws + 52 * MB);   // 64 MB
  ushort_t* qbuf  = (ushort_t*)(ws + 116 * MB);  // 32 MB
  ushort_t* kbuf  = (ushort_t*)(ws + 148 * MB);  // 64 MB
  ushort_t* vbuf  = (ushort_t*)(ws + 212 * MB);  // 64 MB
  ushort_t* amatT = (ushort_t*)(ws + 276 * MB);  // 4 MB
  ushort_t* attnb = (ushort_t*)(ws + 280 * MB);  // 32 MB
  ushort_t* ybr   = (ushort_t*)(ws + 312 * MB);  // 32 MB (post-residual)
  ushort_t* ybnA  = (ushort_t*)(ws + 344 * MB);  // 32 MB (post-LN1)
  ushort_t* ybnB  = (ushort_t*)(ws + 376 * MB);  // 32 MB (post-LN2)
  ushort_t* hbuf  = (ushort_t*)(ws + 408 * MB);  // 32 MB
  float*    pbuf  = (float*)(ws + 440 * MB);     // 32 MB (ktv partials)
  ushort_t* bn1   = attnb;                       // reuse (16 MB)
  ushort_t* bn2   = qbuf;                        // reuse (16 MB)

  // ---- prep ----
  cast_bf16<<<16384, 256, 0, stream>>>(y0, y0b);
  cast_bf16<<<32768, 256, 0, stream>>>(mem, memb);
  transpose_cast<<<dim3(4, 32, 8), 256, 0, stream>>>(Wq1, wcat1);
  transpose_cast<<<dim3(4, 32, 8), 256, 0, stream>>>(Wk1, wcat1 + (1 << 20));
  transpose_cast<<<dim3(4, 32, 8), 256, 0, stream>>>(Wv1, wcat1 + (2 << 20));
  transpose_cast<<<dim3(4, 32, 8), 256, 0, stream>>>(Wk2, wkv2);
  transpose_cast<<<dim3(4, 32, 8), 256, 0, stream>>>(Wv2, wkv2 + (1 << 20));
  transpose_cast<<<dim3(4, 32, 8), 256, 0, stream>>>(Wq2, wq2t);
  cast_bf16<<<1024, 256, 0, stream>>>(Wo1, wo1b);
  cast_bf16<<<1024, 256, 0, stream>>>(Wo2, wo2b);
  cast_bf16<<<512, 256, 0, stream>>>(E1, e1b);
  cast_bf16<<<512, 256, 0, stream>>>(D1, d1b);
  cast_bf16<<<512, 256, 0, stream>>>(E2, e2b);
  cast_bf16<<<512, 256, 0, stream>>>(D2, d2b);

  // ---- phase 1: masked self linear-attention ----
  gemm_bb<ST_QKV><<<dim3(24, 128, 1), 256, 0, stream>>>(
      y0b, wcat1, nullptr, qbuf, kbuf, vbuf, NB * ST, 3072, DIM, 0, 0,
      10, /*sm Q,K*/ 0b011, /*mask Q*/ 0b001);
  gemm_ktv<<<dim3(128, 2), 256, 0, stream>>>(kbuf, vbuf, pbuf, ST, 512);
  ktv_reduce<<<2048, 256, 0, stream>>>(pbuf, amatT, 2);
  gemm_bb<ST_SCR><<<dim3(1, 8, 128), 256, 0, stream>>>(
      qbuf, amatT, nullptr, attnb, nullptr, nullptr,
      ST, DQh, DQh, (long)ST * DQh, 16384, 0, 0, 0);
  gemm_bb<ST_RESB><<<dim3(8, 128, 1), 256, 0, stream>>>(
      attnb, wo1b, y0b, ybr, nullptr, nullptr, NB * ST, DIM, DIM, 0, 0, 0, 0, 0);
  layernorm_b<<<NB * ST, 256, 0, stream>>>(ybr, g1, b1, ybnA, nullptr);

  // ---- phase 2: cross linear-attention ----
  gemm_bb<ST_QKV><<<dim3(8, 128, 1), 256, 0, stream>>>(
      ybnA, wq2t, nullptr, qbuf, nullptr, nullptr, NB * ST, 1024, DIM, 0, 0,
      10, 0b001, 0);
  gemm_bb<ST_QKV><<<dim3(16, 256, 1), 256, 0, stream>>>(
      memb, wkv2, nullptr, kbuf, vbuf, nullptr, NB * SM, 2048, DIM, 0, 0,
      11, 0b001, 0);
  gemm_ktv<<<dim3(128, 4), 256, 0, stream>>>(kbuf, vbuf, pbuf, SM, 512);
  ktv_reduce<<<2048, 256, 0, stream>>>(pbuf, amatT, 4);
  gemm_bb<ST_SCR><<<dim3(1, 8, 128), 256, 0, stream>>>(
      qbuf, amatT, nullptr, attnb, nullptr, nullptr,
      ST, DQh, DQh, (long)ST * DQh, 16384, 0, 0, 0);
  gemm_bb<ST_RESB><<<dim3(8, 128, 1), 256, 0, stream>>>(
      attnb, wo2b, ybnA, ybr, nullptr, nullptr, NB * ST, DIM, DIM, 0, 0, 0, 0, 0);
  layernorm_b<<<NB * ST, 256, 0, stream>>>(ybr, g2, b2, ybnB, nullptr);

  // ---- phase 3: LFFN ----
  gemm_bb<ST_BF16><<<dim3(4, 128, 1), 256, 0, stream>>>(
      ybnB, e1b, nullptr, bn1, nullptr, nullptr, NB * ST, 512, DIM, 0, 0, 0, 0, 0);
  gemm_bb<ST_SWISH><<<dim3(8, 128, 1), 256, 0, stream>>>(
      bn1, d1b, nullptr, hbuf, nullptr, nullptr, NB * ST, DIM, 512, 0, 0, 0, 0, 0);
  gemm_bb<ST_BF16><<<dim3(4, 128, 1), 256, 0, stream>>>(
      hbuf, e2b, nullptr, bn2, nullptr, nullptr, NB * ST, 512, DIM, 0, 0, 0, 0, 0);
  gemm_bb<ST_RESB><<<dim3(8, 128, 1), 256, 0, stream>>>(
      bn2, d2b, ybnB, ybr, nullptr, nullptr, NB * ST, DIM, 512, 0, 0, 0, 0, 0);
  layernorm_b<<<NB * ST, 256, 0, stream>>>(ybr, g3, b3, nullptr, (float*)d_out);
}

// Round 5
// 871.562 us; speedup vs baseline: 1.1726x; 1.1000x over previous
//
#include <hip/hip_runtime.h>
#include <hip/hip_bf16.h>

#define DEVI __device__ __forceinline__

typedef __bf16 bfrag __attribute__((ext_vector_type(8)));
typedef unsigned short us8 __attribute__((ext_vector_type(8)));
typedef float f32x4 __attribute__((ext_vector_type(4)));
typedef unsigned short ushort_t;

static constexpr int NB  = 16;
static constexpr int NH  = 8;
static constexpr int DIM = 1024;
static constexpr int DQh = 128;
static constexpr int ST  = 1024;
static constexpr int SM  = 2048;
static constexpr float INV_SCALE = 0.29730177875068026f; // 1 / 128^0.25
static constexpr float LN_EPS = 1e-5f;

DEVI ushort_t f2bf(float f) {
  __hip_bfloat16 h = __float2bfloat16(f);
  return __builtin_bit_cast(ushort_t, h);
}
DEVI float bf2f(ushort_t u) {
  return __bfloat162float(__builtin_bit_cast(__hip_bfloat16, u));
}
DEVI bfrag ldfrag(const ushort_t* p) {
  return __builtin_bit_cast(bfrag, *(const us8*)p);
}
DEVI void gl16(const ushort_t* g, ushort_t* l) {
  __builtin_amdgcn_global_load_lds(
      (const __attribute__((address_space(1))) void*)g,
      (__attribute__((address_space(3))) void*)l, 16, 0, 0);
}

enum { ST_BF16 = 0, ST_SWISH = 1, ST_F32RES = 2, ST_SCR = 3 };

// ---------------------------------------------------------------------------
// Projection GEMM with fused wave-local softmax. 128x128 tile, 4 waves in a
// 4x1 (M) arrangement: wave w computes rows [w*32, w*32+32) x all 128 cols,
// so the head-dim softmax (over the 128-wide block column = one head) is
// fully wave-local: max/sum over 8 frags + shfl_xor over frow. Scatters to
// per-(h,b) [S][128] buffers; optional causal head-dim mask.
// ---------------------------------------------------------------------------
__global__ __launch_bounds__(256, 4)
void gemm_qkv(const ushort_t* __restrict__ A, const ushort_t* __restrict__ Bt,
              ushort_t* __restrict__ P0, ushort_t* __restrict__ P1,
              ushort_t* __restrict__ P2,
              int M, int N, int K, int logS, int smflags, int maskflags)
{
  __shared__ ushort_t As[128][32];
  __shared__ ushort_t Bs[128][32];
  const int tid = threadIdx.x;
  int bx = blockIdx.x, by = blockIdx.y;
  {
    const int gx = gridDim.x;
    const int nwg = gx * gridDim.y;
    int bid = by * gx + bx;
    if ((nwg & 7) == 0) bid = (bid & 7) * (nwg >> 3) + (bid >> 3);  // XCD swizzle
    bx = bid % gx; by = bid / gx;
  }
  const int m0 = by * 128, n0 = bx * 128;

  const int lane = tid & 63;
  const int w = tid >> 6;
  const int wr = w * 32;
  const int frow = lane & 15;
  const int q = lane >> 4;

  const int grow = lane >> 2;
  const int gk = ((lane & 3) ^ ((lane >> 3) & 3)) * 8;
  const ushort_t* Ag = A + (long)(m0 + w * 32 + grow) * K + gk;
  const ushort_t* Bg = Bt + (long)(n0 + w * 32 + grow) * K + gk;

  f32x4 acc[2][8];
  #pragma unroll
  for (int i = 0; i < 2; ++i)
    #pragma unroll
    for (int j = 0; j < 8; ++j) acc[i][j] = f32x4{0.f, 0.f, 0.f, 0.f};

  const int kqs = (frow >> 1) & 3;
  for (int k0 = 0; k0 < K; k0 += 32) {
    __syncthreads();
    gl16(Ag + k0,                &As[w * 32][0]);
    gl16(Ag + k0 + (long)16 * K, &As[w * 32 + 16][0]);
    gl16(Bg + k0,                &Bs[w * 32][0]);
    gl16(Bg + k0 + (long)16 * K, &Bs[w * 32 + 16][0]);
    __syncthreads();
    const int kq = (q ^ kqs) * 8;
    const bfrag af0 = ldfrag(&As[wr + frow][kq]);
    const bfrag af1 = ldfrag(&As[wr + 16 + frow][kq]);
    #pragma unroll
    for (int j = 0; j < 8; ++j) {
      const bfrag bf = ldfrag(&Bs[j * 16 + frow][kq]);
      acc[0][j] = __builtin_amdgcn_mfma_f32_16x16x32_bf16(af0, bf, acc[0][j], 0, 0, 0);
      acc[1][j] = __builtin_amdgcn_mfma_f32_16x16x32_bf16(af1, bf, acc[1][j], 0, 0, 0);
    }
  }

  const int sel = n0 >> 10;  // block-uniform
  const bool dosm   = (smflags >> sel) & 1;
  const bool domask = (maskflags >> sel) & 1;
  const int h = (n0 >> 7) & 7;
  ushort_t* __restrict__ Bq = (sel == 0) ? P0 : ((sel == 1) ? P1 : P2);
  const int S = 1 << logS;
  #pragma unroll
  for (int i = 0; i < 2; ++i) {
    #pragma unroll
    for (int e = 0; e < 4; ++e) {
      const int gm = m0 + wr + i * 16 + q * 4 + e;
      const int b = gm >> logS, s = gm & (S - 1);
      float v[8];
      #pragma unroll
      for (int j = 0; j < 8; ++j) v[j] = acc[i][j][e];
      if (dosm) {
        #pragma unroll
        for (int j = 0; j < 8; ++j) {
          v[j] *= INV_SCALE;
          if (domask && (j * 16 + frow) > s) v[j] = -3.0e38f;
        }
        float mx = v[0];
        #pragma unroll
        for (int j = 1; j < 8; ++j) mx = fmaxf(mx, v[j]);
        mx = fmaxf(mx, __shfl_xor(mx, 1));
        mx = fmaxf(mx, __shfl_xor(mx, 2));
        mx = fmaxf(mx, __shfl_xor(mx, 4));
        mx = fmaxf(mx, __shfl_xor(mx, 8));
        float sm = 0.f;
        #pragma unroll
        for (int j = 0; j < 8; ++j) { v[j] = __expf(v[j] - mx); sm += v[j]; }
        sm += __shfl_xor(sm, 1);
        sm += __shfl_xor(sm, 2);
        sm += __shfl_xor(sm, 4);
        sm += __shfl_xor(sm, 8);
        const float inv = 1.0f / sm;
        #pragma unroll
        for (int j = 0; j < 8; ++j) v[j] *= inv;
      }
      ushort_t* rowp = Bq + ((long)(h * 16 + b) * S + (long)s) * 128;
      #pragma unroll
      for (int j = 0; j < 8; ++j) rowp[j * 16 + frow] = f2bf(v[j]);
    }
  }
}

// ---------------------------------------------------------------------------
// 128x128-tile bf16 GEMM (m97 structure), 2x2 waves. Epilogues:
//  ST_BF16 / ST_SWISH : bf16 store
//  ST_F32RES          : + f32 residual, f32 store
//  ST_SCR             : torch .view head-merge scramble, bf16 store
// ---------------------------------------------------------------------------
template<int STORE>
__global__ __launch_bounds__(256, 2)
void gemm_bb(const ushort_t* __restrict__ A, const ushort_t* __restrict__ Bt,
             const float* __restrict__ Res,
             ushort_t* __restrict__ P0, float* __restrict__ Cf,
             int M, int N, int K, long aZ, long bZ)
{
  __shared__ ushort_t As[128][32];
  __shared__ ushort_t Bs[128][32];
  const int tid = threadIdx.x;
  int bx = blockIdx.x, by = blockIdx.y;
  if (gridDim.z == 1) {
    const int gx = gridDim.x;
    const int nwg = gx * gridDim.y;
    int bid = by * gx + bx;
    if ((nwg & 7) == 0) bid = (bid & 7) * (nwg >> 3) + (bid >> 3);
    bx = bid % gx; by = bid / gx;
  }
  const int z = blockIdx.z;
  const int m0 = by * 128, n0 = bx * 128;
  A  += aZ * (long)z;
  Bt += bZ * (long)z;

  const int lane = tid & 63;
  const int w = tid >> 6;
  const int wr = (w >> 1) * 64, wc = (w & 1) * 64;
  const int frow = lane & 15;
  const int q = lane >> 4;

  const int grow = lane >> 2;
  const int gk = ((lane & 3) ^ ((lane >> 3) & 3)) * 8;
  const ushort_t* Ag = A + (long)(m0 + w * 32 + grow) * K + gk;
  const ushort_t* Bg = Bt + (long)(n0 + w * 32 + grow) * K + gk;

  f32x4 acc[4][4];
  #pragma unroll
  for (int i = 0; i < 4; ++i)
    #pragma unroll
    for (int j = 0; j < 4; ++j) acc[i][j] = f32x4{0.f, 0.f, 0.f, 0.f};

  const int kqs = (frow >> 1) & 3;
  for (int k0 = 0; k0 < K; k0 += 32) {
    __syncthreads();
    gl16(Ag + k0,                &As[w * 32][0]);
    gl16(Ag + k0 + (long)16 * K, &As[w * 32 + 16][0]);
    gl16(Bg + k0,                &Bs[w * 32][0]);
    gl16(Bg + k0 + (long)16 * K, &Bs[w * 32 + 16][0]);
    __syncthreads();
    const int kq = (q ^ kqs) * 8;
    bfrag af[4], bf[4];
    #pragma unroll
    for (int i = 0; i < 4; ++i) af[i] = ldfrag(&As[wr + i * 16 + frow][kq]);
    #pragma unroll
    for (int j = 0; j < 4; ++j) bf[j] = ldfrag(&Bs[wc + j * 16 + frow][kq]);
    #pragma unroll
    for (int i = 0; i < 4; ++i)
      #pragma unroll
      for (int j = 0; j < 4; ++j)
        acc[i][j] = __builtin_amdgcn_mfma_f32_16x16x32_bf16(af[i], bf[j], acc[i][j], 0, 0, 0);
  }

  const int rb = q * 4;
  #pragma unroll
  for (int i = 0; i < 4; ++i) {
    #pragma unroll
    for (int j = 0; j < 4; ++j) {
      #pragma unroll
      for (int e = 0; e < 4; ++e) {
        const int gm = m0 + wr + i * 16 + rb + e;
        const int gn = n0 + wc + j * 16 + frow;
        float val = acc[i][j][e];
        if constexpr (STORE == ST_SWISH) val = val / (1.0f + __expf(-val));
        if constexpr (STORE == ST_F32RES) {
          Cf[(long)gm * N + gn] = val + Res[(long)gm * N + gn];
        } else if constexpr (STORE == ST_SCR) {
          const int b = z & 15, hh = z >> 4;
          P0[(long)b * (ST * DIM) + (long)(hh * 128 + (gm >> 3)) * DIM +
             (gm & 7) * 128 + gn] = f2bf(val);
        } else {
          P0[(long)gm * N + gn] = f2bf(val);
        }
      }
    }
  }
}

// ---------------------------------------------------------------------------
// Split-S K^T·V: P[ch][z][e][d] = sum_{s in chunk} V[z][s][e]*softK[z][s][d]
// ---------------------------------------------------------------------------
__global__ __launch_bounds__(256, 2)
void gemm_ktv(const ushort_t* __restrict__ Kp, const ushort_t* __restrict__ Vp,
              float* __restrict__ P, int S, int SC)
{
  __shared__ ushort_t As[128][40];
  __shared__ ushort_t Bs[128][40];
  const int tid = threadIdx.x;
  const int z = blockIdx.x;
  const int ch = blockIdx.y;
  const long base = ((long)z * S + (long)ch * SC) * DQh;
  const ushort_t* Vb = Vp + base;
  const ushort_t* Kb = Kp + base;
  const int lane = tid & 63;
  const int wr = ((tid >> 6) >> 1) * 64, wc = ((tid >> 6) & 1) * 64;
  const int frow = lane & 15, fk = (lane >> 4) * 8;
  const int c = tid & 127;
  const int sr0 = tid >> 7;

  f32x4 acc[4][4];
  #pragma unroll
  for (int i = 0; i < 4; ++i)
    #pragma unroll
    for (int j = 0; j < 4; ++j) acc[i][j] = f32x4{0.f, 0.f, 0.f, 0.f};

  for (int s0 = 0; s0 < SC; s0 += 32) {
    __syncthreads();
    #pragma unroll
    for (int p = 0; p < 16; ++p) {
      const int sr = sr0 + p * 2;
      As[c][sr] = Vb[(long)(s0 + sr) * DQh + c];
      Bs[c][sr] = Kb[(long)(s0 + sr) * DQh + c];
    }
    __syncthreads();
    bfrag af[4], bfv[4];
    #pragma unroll
    for (int i = 0; i < 4; ++i) af[i]  = ldfrag(&As[wr + i * 16 + frow][fk]);
    #pragma unroll
    for (int j = 0; j < 4; ++j) bfv[j] = ldfrag(&Bs[wc + j * 16 + frow][fk]);
    #pragma unroll
    for (int i = 0; i < 4; ++i)
      #pragma unroll
      for (int j = 0; j < 4; ++j)
        acc[i][j] = __builtin_amdgcn_mfma_f32_16x16x32_bf16(af[i], bfv[j], acc[i][j], 0, 0, 0);
  }
  float* Pz = P + ((long)ch * 128 + z) * 16384;
  const int rb = (lane >> 4) * 4;
  #pragma unroll
  for (int i = 0; i < 4; ++i)
    #pragma unroll
    for (int j = 0; j < 4; ++j)
      #pragma unroll
      for (int e = 0; e < 4; ++e)
        Pz[(long)(wr + i * 16 + rb + e) * 128 + (wc + j * 16 + frow)] = acc[i][j][e];
}

__global__ __launch_bounds__(256)
void ktv_reduce(const float* __restrict__ P, ushort_t* __restrict__ AT, int nch)
{
  const long i = ((long)blockIdx.x * 256 + threadIdx.x) * 4;
  float4 s = *(const float4*)(P + i);
  for (int c = 1; c < nch; ++c) {
    const float4 v = *(const float4*)(P + (long)c * 2097152 + i);
    s.x += v.x; s.y += v.y; s.z += v.z; s.w += v.w;
  }
  ushort4 o = make_ushort4(f2bf(s.x), f2bf(s.y), f2bf(s.z), f2bf(s.w));
  *(ushort4*)(AT + i) = o;
}

// ---------------------------------------------------------------------------
// LayerNorm over DIM=1024, f32 in; f32 out (Y) + optional bf16 copy (Yb).
// ---------------------------------------------------------------------------
__global__ __launch_bounds__(256)
void layernorm_k(const float* __restrict__ X, const float* __restrict__ G,
                 const float* __restrict__ Bta, float* __restrict__ Y,
                 ushort_t* __restrict__ Yb)
{
  const int row = blockIdx.x;
  const int t = threadIdx.x;
  const float4 v = *(const float4*)(X + (long)row * DIM + t * 4);
  float s  = v.x + v.y + v.z + v.w;
  float sq = v.x * v.x + v.y * v.y + v.z * v.z + v.w * v.w;
  #pragma unroll
  for (int o = 32; o; o >>= 1) { s += __shfl_xor(s, o); sq += __shfl_xor(sq, o); }
  __shared__ float ps[4], pq[4];
  if ((t & 63) == 0) { ps[t >> 6] = s; pq[t >> 6] = sq; }
  __syncthreads();
  s  = ps[0] + ps[1] + ps[2] + ps[3];
  sq = pq[0] + pq[1] + pq[2] + pq[3];
  const float mean = s * (1.0f / DIM);
  const float var  = sq * (1.0f / DIM) - mean * mean;
  const float rstd = rsqrtf(var + LN_EPS);
  const float4 gv = *(const float4*)(G + t * 4);
  const float4 bv = *(const float4*)(Bta + t * 4);
  float4 o;
  o.x = (v.x - mean) * rstd * gv.x + bv.x;
  o.y = (v.y - mean) * rstd * gv.y + bv.y;
  o.z = (v.z - mean) * rstd * gv.z + bv.z;
  o.w = (v.w - mean) * rstd * gv.w + bv.w;
  *(float4*)(Y + (long)row * DIM + t * 4) = o;
  if (Yb) {
    ushort4 ob = make_ushort4(f2bf(o.x), f2bf(o.y), f2bf(o.z), f2bf(o.w));
    *(ushort4*)(Yb + (long)row * DIM + t * 4) = ob;
  }
}

__global__ __launch_bounds__(256)
void transpose_cast(const float* __restrict__ W, ushort_t* __restrict__ Wt)
{
  __shared__ float tile[32][33];
  const int z = blockIdx.z;
  const int kb = blockIdx.y * 32;
  const int nb = blockIdx.x * 32;
  const float* src = W + (long)z * DIM * DQh;
  ushort_t* dst = Wt + (long)z * DIM * DQh;
  const int tx = threadIdx.x & 31;
  const int ty = threadIdx.x >> 5;
  #pragma unroll
  for (int r = 0; r < 32; r += 8)
    tile[ty + r][tx] = src[(long)(kb + ty + r) * DQh + nb + tx];
  __syncthreads();
  #pragma unroll
  for (int r = 0; r < 32; r += 8)
    dst[(long)(nb + ty + r) * DIM + kb + tx] = f2bf(tile[tx][ty + r]);
}

__global__ __launch_bounds__(256)
void cast_bf16(const float* __restrict__ X, ushort_t* __restrict__ Yq)
{
  const long i = ((long)blockIdx.x * 256 + threadIdx.x) * 4;
  const float4 v = *(const float4*)(X + i);
  ushort4 sv = make_ushort4(f2bf(v.x), f2bf(v.y), f2bf(v.z), f2bf(v.w));
  *(ushort4*)(Yq + i) = sv;
}

// ---------------------------------------------------------------------------

extern "C" void kernel_launch(void* const* d_in, const int* in_sizes, int n_in,
                              void* d_out, int out_size, void* d_ws, size_t ws_size,
                              hipStream_t stream)
{
  (void)in_sizes; (void)n_in; (void)out_size; (void)ws_size;
  const float* mem = (const float*)d_in[0];
  const float* y0  = (const float*)d_in[1];
  const float* Wq1 = (const float*)d_in[2];
  const float* Wk1 = (const float*)d_in[3];
  const float* Wv1 = (const float*)d_in[4];
  const float* Wo1 = (const float*)d_in[5];
  const float* Wq2 = (const float*)d_in[6];
  const float* Wk2 = (const float*)d_in[7];
  const float* Wv2 = (const float*)d_in[8];
  const float* Wo2 = (const float*)d_in[9];
  const float* E1  = (const float*)d_in[10];
  const float* D1  = (const float*)d_in[11];
  const float* E2  = (const float*)d_in[12];
  const float* D2  = (const float*)d_in[13];
  const float* g1  = (const float*)d_in[14];
  const float* b1  = (const float*)d_in[15];
  const float* g2  = (const float*)d_in[16];
  const float* b2  = (const float*)d_in[17];
  const float* g3  = (const float*)d_in[18];
  const float* b3  = (const float*)d_in[19];

  char* ws = (char*)d_ws;
  const size_t MB = 1ull << 20;
  ushort_t* wcat1 = (ushort_t*)(ws + 0 * MB);    // [3072][1024]
  ushort_t* wkv2  = (ushort_t*)(ws + 6 * MB);    // [2048][1024]
  ushort_t* wq2t  = (ushort_t*)(ws + 10 * MB);
  ushort_t* wo1b  = (ushort_t*)(ws + 12 * MB);
  ushort_t* wo2b  = (ushort_t*)(ws + 14 * MB);
  ushort_t* e1b   = (ushort_t*)(ws + 16 * MB);
  ushort_t* d1b   = (ushort_t*)(ws + 17 * MB);
  ushort_t* e2b   = (ushort_t*)(ws + 18 * MB);
  ushort_t* d2b   = (ushort_t*)(ws + 19 * MB);
  ushort_t* y0b   = (ushort_t*)(ws + 20 * MB);   // 32 MB
  ushort_t* memb  = (ushort_t*)(ws + 52 * MB);   // 64 MB
  ushort_t* qbuf  = (ushort_t*)(ws + 116 * MB);  // 32 MB
  ushort_t* kbuf  = (ushort_t*)(ws + 148 * MB);  // 64 MB
  ushort_t* vbuf  = (ushort_t*)(ws + 212 * MB);  // 64 MB
  ushort_t* amatT = (ushort_t*)(ws + 276 * MB);  // 4 MB
  ushort_t* attnb = (ushort_t*)(ws + 280 * MB);  // 32 MB
  float*    ybuf  = (float*)(ws + 312 * MB);     // 64 MB (f32 residual/LN)
  ushort_t* ybf   = (ushort_t*)(ws + 376 * MB);  // 32 MB
  ushort_t* hbuf  = (ushort_t*)(ws + 408 * MB);  // 32 MB
  float*    pbuf  = (float*)(ws + 440 * MB);     // 32 MB (ktv partials)
  ushort_t* bn1   = attnb;                       // reuse (16 MB)
  ushort_t* bn2   = qbuf;                        // reuse (16 MB)

  // ---- prep ----
  cast_bf16<<<16384, 256, 0, stream>>>(y0, y0b);
  cast_bf16<<<32768, 256, 0, stream>>>(mem, memb);
  transpose_cast<<<dim3(4, 32, 8), 256, 0, stream>>>(Wq1, wcat1);
  transpose_cast<<<dim3(4, 32, 8), 256, 0, stream>>>(Wk1, wcat1 + (1 << 20));
  transpose_cast<<<dim3(4, 32, 8), 256, 0, stream>>>(Wv1, wcat1 + (2 << 20));
  transpose_cast<<<dim3(4, 32, 8), 256, 0, stream>>>(Wk2, wkv2);
  transpose_cast<<<dim3(4, 32, 8), 256, 0, stream>>>(Wv2, wkv2 + (1 << 20));
  transpose_cast<<<dim3(4, 32, 8), 256, 0, stream>>>(Wq2, wq2t);
  cast_bf16<<<1024, 256, 0, stream>>>(Wo1, wo1b);
  cast_bf16<<<1024, 256, 0, stream>>>(Wo2, wo2b);
  cast_bf16<<<512, 256, 0, stream>>>(E1, e1b);
  cast_bf16<<<512, 256, 0, stream>>>(D1, d1b);
  cast_bf16<<<512, 256, 0, stream>>>(E2, e2b);
  cast_bf16<<<512, 256, 0, stream>>>(D2, d2b);

  // ---- phase 1: masked self linear-attention ----
  gemm_qkv<<<dim3(24, 128), 256, 0, stream>>>(
      y0b, wcat1, qbuf, kbuf, vbuf, NB * ST, 3072, DIM,
      10, /*sm Q,K*/ 0b011, /*mask Q*/ 0b001);
  gemm_ktv<<<dim3(128, 2), 256, 0, stream>>>(kbuf, vbuf, pbuf, ST, 512);
  ktv_reduce<<<2048, 256, 0, stream>>>(pbuf, amatT, 2);
  gemm_bb<ST_SCR><<<dim3(1, 8, 128), 256, 0, stream>>>(
      qbuf, amatT, nullptr, attnb, nullptr, ST, DQh, DQh, (long)ST * DQh, 16384);
  gemm_bb<ST_F32RES><<<dim3(8, 128, 1), 256, 0, stream>>>(
      attnb, wo1b, y0, nullptr, ybuf, NB * ST, DIM, DIM, 0, 0);
  layernorm_k<<<NB * ST, 256, 0, stream>>>(ybuf, g1, b1, ybuf, ybf);

  // ---- phase 2: cross linear-attention ----
  gemm_qkv<<<dim3(8, 128), 256, 0, stream>>>(
      ybf, wq2t, qbuf, nullptr, nullptr, NB * ST, 1024, DIM, 10, 0b001, 0);
  gemm_qkv<<<dim3(16, 256), 256, 0, stream>>>(
      memb, wkv2, kbuf, vbuf, nullptr, NB * SM, 2048, DIM, 11, 0b001, 0);
  gemm_ktv<<<dim3(128, 4), 256, 0, stream>>>(kbuf, vbuf, pbuf, SM, 512);
  ktv_reduce<<<2048, 256, 0, stream>>>(pbuf, amatT, 4);
  gemm_bb<ST_SCR><<<dim3(1, 8, 128), 256, 0, stream>>>(
      qbuf, amatT, nullptr, attnb, nullptr, ST, DQh, DQh, (long)ST * DQh, 16384);
  gemm_bb<ST_F32RES><<<dim3(8, 128, 1), 256, 0, stream>>>(
      attnb, wo2b, ybuf, nullptr, ybuf, NB * ST, DIM, DIM, 0, 0);
  layernorm_k<<<NB * ST, 256, 0, stream>>>(ybuf, g2, b2, ybuf, ybf);

  // ---- phase 3: LFFN ----
  gemm_bb<ST_BF16><<<dim3(4, 128, 1), 256, 0, stream>>>(
      ybf, e1b, nullptr, bn1, nullptr, NB * ST, 512, DIM, 0, 0);
  gemm_bb<ST_SWISH><<<dim3(8, 128, 1), 256, 0, stream>>>(
      bn1, d1b, nullptr, hbuf, nullptr, NB * ST, DIM, 512, 0, 0);
  gemm_bb<ST_BF16><<<dim3(4, 128, 1), 256, 0, stream>>>(
      hbuf, e2b, nullptr, bn2, nullptr, NB * ST, 512, DIM, 0, 0);
  gemm_bb<ST_F32RES><<<dim3(8, 128, 1), 256, 0, stream>>>(
      bn2, d2b, ybuf, nullptr, ybuf, NB * ST, DIM, 512, 0, 0);
  layernorm_k<<<NB * ST, 256, 0, stream>>>(ybuf, g3, b3, (float*)d_out, nullptr);
}

// Round 6
// 868.344 us; speedup vs baseline: 1.1770x; 1.0037x over previous
//
#include <hip/hip_runtime.h>
#include <hip/hip_bf16.h>

#define DEVI __device__ __forceinline__

typedef __bf16 bfrag __attribute__((ext_vector_type(8)));
typedef unsigned short us8 __attribute__((ext_vector_type(8)));
typedef float f32x4 __attribute__((ext_vector_type(4)));
typedef unsigned short ushort_t;

static constexpr int NB  = 16;
static constexpr int NH  = 8;
static constexpr int DIM = 1024;
static constexpr int DQh = 128;
static constexpr int ST  = 1024;
static constexpr int SM  = 2048;
static constexpr float INV_SCALE = 0.29730177875068026f; // 1 / 128^0.25
static constexpr float LN_EPS = 1e-5f;

DEVI ushort_t f2bf(float f) {
  __hip_bfloat16 h = __float2bfloat16(f);
  return __builtin_bit_cast(ushort_t, h);
}
DEVI float bf2f(ushort_t u) {
  return __bfloat162float(__builtin_bit_cast(__hip_bfloat16, u));
}
DEVI bfrag ldfrag(const ushort_t* p) {
  return __builtin_bit_cast(bfrag, *(const us8*)p);
}
DEVI void gl16(const ushort_t* g, ushort_t* l) {
  __builtin_amdgcn_global_load_lds(
      (const __attribute__((address_space(1))) void*)g,
      (__attribute__((address_space(3))) void*)l, 16, 0, 0);
}

enum { ST_BF16 = 0, ST_SWISH = 1, ST_F32RES = 2 };

// ---------------------------------------------------------------------------
// K/V projection GEMM with fused wave-local softmax (R5 structure).
// 128x128 tile, 4 waves 4x1 (M): wave w owns rows [w*32,w*32+32) x 128 cols
// (one head). Softmax over head dim is wave-local. Scatter to per-(h,b)
// [S][128] buffers.
// ---------------------------------------------------------------------------
__global__ __launch_bounds__(256, 4)
void gemm_qkv(const ushort_t* __restrict__ A, const ushort_t* __restrict__ Bt,
              ushort_t* __restrict__ P0, ushort_t* __restrict__ P1,
              int M, int N, int K, int logS, int smflags)
{
  __shared__ ushort_t As[128][32];
  __shared__ ushort_t Bs[128][32];
  const int tid = threadIdx.x;
  int bx = blockIdx.x, by = blockIdx.y;
  {
    const int gx = gridDim.x;
    const int nwg = gx * gridDim.y;
    int bid = by * gx + bx;
    if ((nwg & 7) == 0) bid = (bid & 7) * (nwg >> 3) + (bid >> 3);  // XCD swizzle
    bx = bid % gx; by = bid / gx;
  }
  const int m0 = by * 128, n0 = bx * 128;

  const int lane = tid & 63;
  const int w = tid >> 6;
  const int wr = w * 32;
  const int frow = lane & 15;
  const int q = lane >> 4;

  const int grow = lane >> 2;
  const int gk = ((lane & 3) ^ ((lane >> 3) & 3)) * 8;
  const ushort_t* Ag = A + (long)(m0 + w * 32 + grow) * K + gk;
  const ushort_t* Bg = Bt + (long)(n0 + w * 32 + grow) * K + gk;

  f32x4 acc[2][8];
  #pragma unroll
  for (int i = 0; i < 2; ++i)
    #pragma unroll
    for (int j = 0; j < 8; ++j) acc[i][j] = f32x4{0.f, 0.f, 0.f, 0.f};

  const int kqs = (frow >> 1) & 3;
  for (int k0 = 0; k0 < K; k0 += 32) {
    __syncthreads();
    gl16(Ag + k0,                &As[w * 32][0]);
    gl16(Ag + k0 + (long)16 * K, &As[w * 32 + 16][0]);
    gl16(Bg + k0,                &Bs[w * 32][0]);
    gl16(Bg + k0 + (long)16 * K, &Bs[w * 32 + 16][0]);
    __syncthreads();
    const int kq = (q ^ kqs) * 8;
    const bfrag af0 = ldfrag(&As[wr + frow][kq]);
    const bfrag af1 = ldfrag(&As[wr + 16 + frow][kq]);
    #pragma unroll
    for (int j = 0; j < 8; ++j) {
      const bfrag bf = ldfrag(&Bs[j * 16 + frow][kq]);
      acc[0][j] = __builtin_amdgcn_mfma_f32_16x16x32_bf16(af0, bf, acc[0][j], 0, 0, 0);
      acc[1][j] = __builtin_amdgcn_mfma_f32_16x16x32_bf16(af1, bf, acc[1][j], 0, 0, 0);
    }
  }

  const int sel = n0 >> 10;  // block-uniform
  const bool dosm = (smflags >> sel) & 1;
  const int h = (n0 >> 7) & 7;
  ushort_t* __restrict__ Bq = (sel == 0) ? P0 : P1;
  const int S = 1 << logS;
  #pragma unroll
  for (int i = 0; i < 2; ++i) {
    #pragma unroll
    for (int e = 0; e < 4; ++e) {
      const int gm = m0 + wr + i * 16 + q * 4 + e;
      const int b = gm >> logS, s = gm & (S - 1);
      float v[8];
      #pragma unroll
      for (int j = 0; j < 8; ++j) v[j] = acc[i][j][e];
      if (dosm) {
        #pragma unroll
        for (int j = 0; j < 8; ++j) v[j] *= INV_SCALE;
        float mx = v[0];
        #pragma unroll
        for (int j = 1; j < 8; ++j) mx = fmaxf(mx, v[j]);
        mx = fmaxf(mx, __shfl_xor(mx, 1));
        mx = fmaxf(mx, __shfl_xor(mx, 2));
        mx = fmaxf(mx, __shfl_xor(mx, 4));
        mx = fmaxf(mx, __shfl_xor(mx, 8));
        float sm = 0.f;
        #pragma unroll
        for (int j = 0; j < 8; ++j) { v[j] = __expf(v[j] - mx); sm += v[j]; }
        sm += __shfl_xor(sm, 1);
        sm += __shfl_xor(sm, 2);
        sm += __shfl_xor(sm, 4);
        sm += __shfl_xor(sm, 8);
        const float inv = 1.0f / sm;
        #pragma unroll
        for (int j = 0; j < 8; ++j) v[j] *= inv;
      }
      ushort_t* rowp = Bq + ((long)(h * 16 + b) * S + (long)s) * 128;
      #pragma unroll
      for (int j = 0; j < 8; ++j) rowp[j * 16 + frow] = f2bf(v[j]);
    }
  }
}

// ---------------------------------------------------------------------------
// Fused Q path: scores = y_tile @ Wq_h^T (K=1024) -> wave-local softmax
// (optional causal head-dim mask) -> P (per-wave swizzled LDS) -> P @ AT_z
// (K=128, AT staged via gl16) -> torch-.view scramble store to attnb.
// One block = 128 rows x one head. Grid (NH, M/128).
// ---------------------------------------------------------------------------
template<bool MASKED>
__global__ __launch_bounds__(256, 3)
void fused_qa(const ushort_t* __restrict__ A, const ushort_t* __restrict__ Wq,
              const ushort_t* __restrict__ AT, ushort_t* __restrict__ Out)
{
  __shared__ ushort_t As[128][32];
  __shared__ ushort_t Bs[128][32];
  __shared__ ushort_t Ps[4][32][128];
  const int tid = threadIdx.x;
  int h = blockIdx.x, by = blockIdx.y;
  {
    const int gx = gridDim.x;
    const int nwg = gx * gridDim.y;
    int bid = by * gx + h;
    if ((nwg & 7) == 0) bid = (bid & 7) * (nwg >> 3) + (bid >> 3);
    h = bid % gx; by = bid / gx;
  }
  const int m0 = by * 128;

  const int lane = tid & 63;
  const int w = tid >> 6;
  const int wr = w * 32;
  const int frow = lane & 15;
  const int q = lane >> 4;

  const int grow = lane >> 2;
  const int gk = ((lane & 3) ^ ((lane >> 3) & 3)) * 8;
  const ushort_t* Ag = A + (long)(m0 + w * 32 + grow) * 1024 + gk;
  const ushort_t* Bg = Wq + (long)(h * 128 + w * 32 + grow) * 1024 + gk;

  f32x4 acc[2][8];
  #pragma unroll
  for (int i = 0; i < 2; ++i)
    #pragma unroll
    for (int j = 0; j < 8; ++j) acc[i][j] = f32x4{0.f, 0.f, 0.f, 0.f};

  const int kqs = (frow >> 1) & 3;
  for (int k0 = 0; k0 < 1024; k0 += 32) {
    __syncthreads();
    gl16(Ag + k0,             &As[w * 32][0]);
    gl16(Ag + k0 + 16 * 1024, &As[w * 32 + 16][0]);
    gl16(Bg + k0,             &Bs[w * 32][0]);
    gl16(Bg + k0 + 16 * 1024, &Bs[w * 32 + 16][0]);
    __syncthreads();
    const int kq = (q ^ kqs) * 8;
    const bfrag af0 = ldfrag(&As[wr + frow][kq]);
    const bfrag af1 = ldfrag(&As[wr + 16 + frow][kq]);
    #pragma unroll
    for (int j = 0; j < 8; ++j) {
      const bfrag bf = ldfrag(&Bs[j * 16 + frow][kq]);
      acc[0][j] = __builtin_amdgcn_mfma_f32_16x16x32_bf16(af0, bf, acc[0][j], 0, 0, 0);
      acc[1][j] = __builtin_amdgcn_mfma_f32_16x16x32_bf16(af1, bf, acc[1][j], 0, 0, 0);
    }
  }

  // softmax + write P to per-wave swizzled LDS
  #pragma unroll
  for (int i = 0; i < 2; ++i) {
    #pragma unroll
    for (int e = 0; e < 4; ++e) {
      const int row32 = i * 16 + q * 4 + e;
      const int srow = (m0 + wr + row32) & (ST - 1);
      float v[8];
      #pragma unroll
      for (int j = 0; j < 8; ++j) {
        v[j] = acc[i][j][e] * INV_SCALE;
        if (MASKED && (j * 16 + frow) > srow) v[j] = -3.0e38f;
      }
      float mx = v[0];
      #pragma unroll
      for (int j = 1; j < 8; ++j) mx = fmaxf(mx, v[j]);
      mx = fmaxf(mx, __shfl_xor(mx, 1));
      mx = fmaxf(mx, __shfl_xor(mx, 2));
      mx = fmaxf(mx, __shfl_xor(mx, 4));
      mx = fmaxf(mx, __shfl_xor(mx, 8));
      float sm = 0.f;
      #pragma unroll
      for (int j = 0; j < 8; ++j) { v[j] = __expf(v[j] - mx); sm += v[j]; }
      sm += __shfl_xor(sm, 1);
      sm += __shfl_xor(sm, 2);
      sm += __shfl_xor(sm, 4);
      sm += __shfl_xor(sm, 8);
      const float inv = 1.0f / sm;
      const int sw = (row32 >> 1) & 3;
      ushort_t* pr = &Ps[w][row32][0];
      #pragma unroll
      for (int j = 0; j < 8; ++j) {
        const int c = j * 16 + frow;
        const int pos = (c & ~31) | ((((c >> 3) & 3) ^ sw) << 3) | (c & 7);
        pr[pos] = f2bf(v[j] * inv);
      }
    }
  }

  // stage 2: P(128x128, per-wave rows) @ AT_z(128e x 128d, [N][K] form)
  f32x4 acc2[2][8];
  #pragma unroll
  for (int i = 0; i < 2; ++i)
    #pragma unroll
    for (int j = 0; j < 8; ++j) acc2[i][j] = f32x4{0.f, 0.f, 0.f, 0.f};

  const ushort_t* Atg = AT + (long)((h << 4) + (m0 >> 10)) * 16384 +
                        (long)(w * 32 + grow) * 128 + gk;
  for (int d0 = 0; d0 < 128; d0 += 32) {
    __syncthreads();
    gl16(Atg + d0,            &Bs[w * 32][0]);
    gl16(Atg + d0 + 16 * 128, &Bs[w * 32 + 16][0]);
    __syncthreads();
    const int kq = (q ^ kqs) * 8;
    const bfrag af0 = ldfrag(&Ps[w][frow][d0 + kq]);
    const bfrag af1 = ldfrag(&Ps[w][16 + frow][d0 + kq]);
    #pragma unroll
    for (int j = 0; j < 8; ++j) {
      const bfrag bf = ldfrag(&Bs[j * 16 + frow][kq]);
      acc2[0][j] = __builtin_amdgcn_mfma_f32_16x16x32_bf16(af0, bf, acc2[0][j], 0, 0, 0);
      acc2[1][j] = __builtin_amdgcn_mfma_f32_16x16x32_bf16(af1, bf, acc2[1][j], 0, 0, 0);
    }
  }

  // scramble store: out[b, h*128 + srow/8, (srow%8)*128 + e]
  ushort_t* ob = Out + (long)(m0 >> 10) * (ST * DIM);
  #pragma unroll
  for (int i = 0; i < 2; ++i) {
    #pragma unroll
    for (int e = 0; e < 4; ++e) {
      const int srow = (m0 + wr + i * 16 + q * 4 + e) & (ST - 1);
      ushort_t* orow = ob + (long)(h * 128 + (srow >> 3)) * DIM + (srow & 7) * 128;
      #pragma unroll
      for (int j = 0; j < 8; ++j)
        orow[j * 16 + frow] = f2bf(acc2[i][j][e]);
    }
  }
}

// ---------------------------------------------------------------------------
// 128x128-tile bf16 GEMM (m97 structure), 2x2 waves.
// ---------------------------------------------------------------------------
template<int STORE>
__global__ __launch_bounds__(256, 2)
void gemm_bb(const ushort_t* __restrict__ A, const ushort_t* __restrict__ Bt,
             const float* __restrict__ Res,
             ushort_t* __restrict__ P0, float* __restrict__ Cf,
             int M, int N, int K)
{
  __shared__ ushort_t As[128][32];
  __shared__ ushort_t Bs[128][32];
  const int tid = threadIdx.x;
  int bx = blockIdx.x, by = blockIdx.y;
  {
    const int gx = gridDim.x;
    const int nwg = gx * gridDim.y;
    int bid = by * gx + bx;
    if ((nwg & 7) == 0) bid = (bid & 7) * (nwg >> 3) + (bid >> 3);
    bx = bid % gx; by = bid / gx;
  }
  const int m0 = by * 128, n0 = bx * 128;

  const int lane = tid & 63;
  const int w = tid >> 6;
  const int wr = (w >> 1) * 64, wc = (w & 1) * 64;
  const int frow = lane & 15;
  const int q = lane >> 4;

  const int grow = lane >> 2;
  const int gk = ((lane & 3) ^ ((lane >> 3) & 3)) * 8;
  const ushort_t* Ag = A + (long)(m0 + w * 32 + grow) * K + gk;
  const ushort_t* Bg = Bt + (long)(n0 + w * 32 + grow) * K + gk;

  f32x4 acc[4][4];
  #pragma unroll
  for (int i = 0; i < 4; ++i)
    #pragma unroll
    for (int j = 0; j < 4; ++j) acc[i][j] = f32x4{0.f, 0.f, 0.f, 0.f};

  const int kqs = (frow >> 1) & 3;
  for (int k0 = 0; k0 < K; k0 += 32) {
    __syncthreads();
    gl16(Ag + k0,                &As[w * 32][0]);
    gl16(Ag + k0 + (long)16 * K, &As[w * 32 + 16][0]);
    gl16(Bg + k0,                &Bs[w * 32][0]);
    gl16(Bg + k0 + (long)16 * K, &Bs[w * 32 + 16][0]);
    __syncthreads();
    const int kq = (q ^ kqs) * 8;
    bfrag af[4], bf[4];
    #pragma unroll
    for (int i = 0; i < 4; ++i) af[i] = ldfrag(&As[wr + i * 16 + frow][kq]);
    #pragma unroll
    for (int j = 0; j < 4; ++j) bf[j] = ldfrag(&Bs[wc + j * 16 + frow][kq]);
    #pragma unroll
    for (int i = 0; i < 4; ++i)
      #pragma unroll
      for (int j = 0; j < 4; ++j)
        acc[i][j] = __builtin_amdgcn_mfma_f32_16x16x32_bf16(af[i], bf[j], acc[i][j], 0, 0, 0);
  }

  const int rb = q * 4;
  #pragma unroll
  for (int i = 0; i < 4; ++i) {
    #pragma unroll
    for (int j = 0; j < 4; ++j) {
      #pragma unroll
      for (int e = 0; e < 4; ++e) {
        const int gm = m0 + wr + i * 16 + rb + e;
        const int gn = n0 + wc + j * 16 + frow;
        float val = acc[i][j][e];
        if constexpr (STORE == ST_SWISH) val = val / (1.0f + __expf(-val));
        if constexpr (STORE == ST_F32RES) {
          Cf[(long)gm * N + gn] = val + Res[(long)gm * N + gn];
        } else {
          P0[(long)gm * N + gn] = f2bf(val);
        }
      }
    }
  }
}

// ---------------------------------------------------------------------------
// Split-S K^T·V: P[ch][z][e][d] = sum_{s in chunk} V[z][s][e]*softK[z][s][d]
// ---------------------------------------------------------------------------
__global__ __launch_bounds__(256, 2)
void gemm_ktv(const ushort_t* __restrict__ Kp, const ushort_t* __restrict__ Vp,
              float* __restrict__ P, int S, int SC)
{
  __shared__ ushort_t As[128][40];
  __shared__ ushort_t Bs[128][40];
  const int tid = threadIdx.x;
  const int z = blockIdx.x;
  const int ch = blockIdx.y;
  const long base = ((long)z * S + (long)ch * SC) * DQh;
  const ushort_t* Vb = Vp + base;
  const ushort_t* Kb = Kp + base;
  const int lane = tid & 63;
  const int wr = ((tid >> 6) >> 1) * 64, wc = ((tid >> 6) & 1) * 64;
  const int frow = lane & 15, fk = (lane >> 4) * 8;
  const int c = tid & 127;
  const int sr0 = tid >> 7;

  f32x4 acc[4][4];
  #pragma unroll
  for (int i = 0; i < 4; ++i)
    #pragma unroll
    for (int j = 0; j < 4; ++j) acc[i][j] = f32x4{0.f, 0.f, 0.f, 0.f};

  for (int s0 = 0; s0 < SC; s0 += 32) {
    __syncthreads();
    #pragma unroll
    for (int p = 0; p < 16; ++p) {
      const int sr = sr0 + p * 2;
      As[c][sr] = Vb[(long)(s0 + sr) * DQh + c];
      Bs[c][sr] = Kb[(long)(s0 + sr) * DQh + c];
    }
    __syncthreads();
    bfrag af[4], bfv[4];
    #pragma unroll
    for (int i = 0; i < 4; ++i) af[i]  = ldfrag(&As[wr + i * 16 + frow][fk]);
    #pragma unroll
    for (int j = 0; j < 4; ++j) bfv[j] = ldfrag(&Bs[wc + j * 16 + frow][fk]);
    #pragma unroll
    for (int i = 0; i < 4; ++i)
      #pragma unroll
      for (int j = 0; j < 4; ++j)
        acc[i][j] = __builtin_amdgcn_mfma_f32_16x16x32_bf16(af[i], bfv[j], acc[i][j], 0, 0, 0);
  }
  float* Pz = P + ((long)ch * 128 + z) * 16384;
  const int rb = (lane >> 4) * 4;
  #pragma unroll
  for (int i = 0; i < 4; ++i)
    #pragma unroll
    for (int j = 0; j < 4; ++j)
      #pragma unroll
      for (int e = 0; e < 4; ++e)
        Pz[(long)(wr + i * 16 + rb + e) * 128 + (wc + j * 16 + frow)] = acc[i][j][e];
}

__global__ __launch_bounds__(256)
void ktv_reduce(const float* __restrict__ P, ushort_t* __restrict__ AT, int nch)
{
  const long i = ((long)blockIdx.x * 256 + threadIdx.x) * 4;
  float4 s = *(const float4*)(P + i);
  for (int c = 1; c < nch; ++c) {
    const float4 v = *(const float4*)(P + (long)c * 2097152 + i);
    s.x += v.x; s.y += v.y; s.z += v.z; s.w += v.w;
  }
  ushort4 o = make_ushort4(f2bf(s.x), f2bf(s.y), f2bf(s.z), f2bf(s.w));
  *(ushort4*)(AT + i) = o;
}

// ---------------------------------------------------------------------------
// LayerNorm over DIM=1024, f32 in; f32 out (Y) + optional bf16 copy (Yb).
// ---------------------------------------------------------------------------
__global__ __launch_bounds__(256)
void layernorm_k(const float* __restrict__ X, const float* __restrict__ G,
                 const float* __restrict__ Bta, float* __restrict__ Y,
                 ushort_t* __restrict__ Yb)
{
  const int row = blockIdx.x;
  const int t = threadIdx.x;
  const float4 v = *(const float4*)(X + (long)row * DIM + t * 4);
  float s  = v.x + v.y + v.z + v.w;
  float sq = v.x * v.x + v.y * v.y + v.z * v.z + v.w * v.w;
  #pragma unroll
  for (int o = 32; o; o >>= 1) { s += __shfl_xor(s, o); sq += __shfl_xor(sq, o); }
  __shared__ float ps[4], pq[4];
  if ((t & 63) == 0) { ps[t >> 6] = s; pq[t >> 6] = sq; }
  __syncthreads();
  s  = ps[0] + ps[1] + ps[2] + ps[3];
  sq = pq[0] + pq[1] + pq[2] + pq[3];
  const float mean = s * (1.0f / DIM);
  const float var  = sq * (1.0f / DIM) - mean * mean;
  const float rstd = rsqrtf(var + LN_EPS);
  const float4 gv = *(const float4*)(G + t * 4);
  const float4 bv = *(const float4*)(Bta + t * 4);
  float4 o;
  o.x = (v.x - mean) * rstd * gv.x + bv.x;
  o.y = (v.y - mean) * rstd * gv.y + bv.y;
  o.z = (v.z - mean) * rstd * gv.z + bv.z;
  o.w = (v.w - mean) * rstd * gv.w + bv.w;
  *(float4*)(Y + (long)row * DIM + t * 4) = o;
  if (Yb) {
    ushort4 ob = make_ushort4(f2bf(o.x), f2bf(o.y), f2bf(o.z), f2bf(o.w));
    *(ushort4*)(Yb + (long)row * DIM + t * 4) = ob;
  }
}

__global__ __launch_bounds__(256)
void transpose_cast(const float* __restrict__ W, ushort_t* __restrict__ Wt)
{
  __shared__ float tile[32][33];
  const int z = blockIdx.z;
  const int kb = blockIdx.y * 32;
  const int nb = blockIdx.x * 32;
  const float* src = W + (long)z * DIM * DQh;
  ushort_t* dst = Wt + (long)z * DIM * DQh;
  const int tx = threadIdx.x & 31;
  const int ty = threadIdx.x >> 5;
  #pragma unroll
  for (int r = 0; r < 32; r += 8)
    tile[ty + r][tx] = src[(long)(kb + ty + r) * DQh + nb + tx];
  __syncthreads();
  #pragma unroll
  for (int r = 0; r < 32; r += 8)
    dst[(long)(nb + ty + r) * DIM + kb + tx] = f2bf(tile[tx][ty + r]);
}

__global__ __launch_bounds__(256)
void cast_bf16(const float* __restrict__ X, ushort_t* __restrict__ Yq)
{
  const long i = ((long)blockIdx.x * 256 + threadIdx.x) * 4;
  const float4 v = *(const float4*)(X + i);
  ushort4 sv = make_ushort4(f2bf(v.x), f2bf(v.y), f2bf(v.z), f2bf(v.w));
  *(ushort4*)(Yq + i) = sv;
}

// ---------------------------------------------------------------------------

extern "C" void kernel_launch(void* const* d_in, const int* in_sizes, int n_in,
                              void* d_out, int out_size, void* d_ws, size_t ws_size,
                              hipStream_t stream)
{
  (void)in_sizes; (void)n_in; (void)out_size; (void)ws_size;
  const float* mem = (const float*)d_in[0];
  const float* y0  = (const float*)d_in[1];
  const float* Wq1 = (const float*)d_in[2];
  const float* Wk1 = (const float*)d_in[3];
  const float* Wv1 = (const float*)d_in[4];
  const float* Wo1 = (const float*)d_in[5];
  const float* Wq2 = (const float*)d_in[6];
  const float* Wk2 = (const float*)d_in[7];
  const float* Wv2 = (const float*)d_in[8];
  const float* Wo2 = (const float*)d_in[9];
  const float* E1  = (const float*)d_in[10];
  const float* D1  = (const float*)d_in[11];
  const float* E2  = (const float*)d_in[12];
  const float* D2  = (const float*)d_in[13];
  const float* g1  = (const float*)d_in[14];
  const float* b1  = (const float*)d_in[15];
  const float* g2  = (const float*)d_in[16];
  const float* b2  = (const float*)d_in[17];
  const float* g3  = (const float*)d_in[18];
  const float* b3  = (const float*)d_in[19];

  char* ws = (char*)d_ws;
  const size_t MB = 1ull << 20;
  ushort_t* wkv1  = (ushort_t*)(ws + 0 * MB);    // [2048][1024] K|V phase1
  ushort_t* wq1t  = (ushort_t*)(ws + 4 * MB);    // [1024][1024]
  ushort_t* wkv2  = (ushort_t*)(ws + 6 * MB);    // [2048][1024]
  ushort_t* wq2t  = (ushort_t*)(ws + 10 * MB);
  ushort_t* wo1b  = (ushort_t*)(ws + 12 * MB);
  ushort_t* wo2b  = (ushort_t*)(ws + 14 * MB);
  ushort_t* e1b   = (ushort_t*)(ws + 16 * MB);
  ushort_t* d1b   = (ushort_t*)(ws + 17 * MB);
  ushort_t* e2b   = (ushort_t*)(ws + 18 * MB);
  ushort_t* d2b   = (ushort_t*)(ws + 19 * MB);
  ushort_t* y0b   = (ushort_t*)(ws + 20 * MB);   // 32 MB
  ushort_t* memb  = (ushort_t*)(ws + 52 * MB);   // 64 MB
  ushort_t* bn2   = (ushort_t*)(ws + 116 * MB);  // 16 MB (LFFN)
  ushort_t* kbuf  = (ushort_t*)(ws + 148 * MB);  // 64 MB
  ushort_t* vbuf  = (ushort_t*)(ws + 212 * MB);  // 64 MB
  ushort_t* amatT = (ushort_t*)(ws + 276 * MB);  // 4 MB
  ushort_t* attnb = (ushort_t*)(ws + 280 * MB);  // 32 MB
  float*    ybuf  = (float*)(ws + 312 * MB);     // 64 MB
  ushort_t* ybf   = (ushort_t*)(ws + 376 * MB);  // 32 MB
  ushort_t* hbuf  = (ushort_t*)(ws + 408 * MB);  // 32 MB
  float*    pbuf  = (float*)(ws + 440 * MB);     // 32 MB
  ushort_t* bn1   = attnb;                       // reuse (16 MB)

  // ---- prep ----
  cast_bf16<<<16384, 256, 0, stream>>>(y0, y0b);
  cast_bf16<<<32768, 256, 0, stream>>>(mem, memb);
  transpose_cast<<<dim3(4, 32, 8), 256, 0, stream>>>(Wk1, wkv1);
  transpose_cast<<<dim3(4, 32, 8), 256, 0, stream>>>(Wv1, wkv1 + (1 << 20));
  transpose_cast<<<dim3(4, 32, 8), 256, 0, stream>>>(Wq1, wq1t);
  transpose_cast<<<dim3(4, 32, 8), 256, 0, stream>>>(Wk2, wkv2);
  transpose_cast<<<dim3(4, 32, 8), 256, 0, stream>>>(Wv2, wkv2 + (1 << 20));
  transpose_cast<<<dim3(4, 32, 8), 256, 0, stream>>>(Wq2, wq2t);
  cast_bf16<<<1024, 256, 0, stream>>>(Wo1, wo1b);
  cast_bf16<<<1024, 256, 0, stream>>>(Wo2, wo2b);
  cast_bf16<<<512, 256, 0, stream>>>(E1, e1b);
  cast_bf16<<<512, 256, 0, stream>>>(D1, d1b);
  cast_bf16<<<512, 256, 0, stream>>>(E2, e2b);
  cast_bf16<<<512, 256, 0, stream>>>(D2, d2b);

  // ---- phase 1: masked self linear-attention ----
  gemm_qkv<<<dim3(16, 128), 256, 0, stream>>>(
      y0b, wkv1, kbuf, vbuf, NB * ST, 2048, DIM, 10, /*sm K*/ 0b01);
  gemm_ktv<<<dim3(128, 2), 256, 0, stream>>>(kbuf, vbuf, pbuf, ST, 512);
  ktv_reduce<<<2048, 256, 0, stream>>>(pbuf, amatT, 2);
  fused_qa<true><<<dim3(8, 128), 256, 0, stream>>>(y0b, wq1t, amatT, attnb);
  gemm_bb<ST_F32RES><<<dim3(8, 128), 256, 0, stream>>>(
      attnb, wo1b, y0, nullptr, ybuf, NB * ST, DIM, DIM);
  layernorm_k<<<NB * ST, 256, 0, stream>>>(ybuf, g1, b1, ybuf, ybf);

  // ---- phase 2: cross linear-attention ----
  gemm_qkv<<<dim3(16, 256), 256, 0, stream>>>(
      memb, wkv2, kbuf, vbuf, NB * SM, 2048, DIM, 11, 0b01);
  gemm_ktv<<<dim3(128, 4), 256, 0, stream>>>(kbuf, vbuf, pbuf, SM, 512);
  ktv_reduce<<<2048, 256, 0, stream>>>(pbuf, amatT, 4);
  fused_qa<false><<<dim3(8, 128), 256, 0, stream>>>(ybf, wq2t, amatT, attnb);
  gemm_bb<ST_F32RES><<<dim3(8, 128), 256, 0, stream>>>(
      attnb, wo2b, ybuf, nullptr, ybuf, NB * ST, DIM, DIM);
  layernorm_k<<<NB * ST, 256, 0, stream>>>(ybuf, g2, b2, ybuf, ybf);

  // ---- phase 3: LFFN ----
  gemm_bb<ST_BF16><<<dim3(4, 128), 256, 0, stream>>>(
      ybf, e1b, nullptr, bn1, nullptr, NB * ST, 512, DIM);
  gemm_bb<ST_SWISH><<<dim3(8, 128), 256, 0, stream>>>(
      bn1, d1b, nullptr, hbuf, nullptr, NB * ST, DIM, 512);
  gemm_bb<ST_BF16><<<dim3(4, 128), 256, 0, stream>>>(
      hbuf, e2b, nullptr, bn2, nullptr, NB * ST, 512, DIM);
  gemm_bb<ST_F32RES><<<dim3(8, 128), 256, 0, stream>>>(
      bn2, d2b, ybuf, nullptr, ybuf, NB * ST, DIM, 512);
  layernorm_k<<<NB * ST, 256, 0, stream>>>(ybuf, g3, b3, (float*)d_out, nullptr);
}